// Round 5
// baseline (2478.757 us; speedup 1.0000x reference)
//
#include <hip/hip_runtime.h>

typedef float f32x4 __attribute__((ext_vector_type(4)));
typedef _Float16 f16x8 __attribute__((ext_vector_type(8)));
typedef _Float16 f16x2 __attribute__((ext_vector_type(2)));

typedef __attribute__((address_space(1))) const unsigned char gbyte;
typedef __attribute__((address_space(3))) unsigned char sbyte;
__device__ __forceinline__ void gload_lds16(const void* gp, void* lp) {
  __builtin_amdgcn_global_load_lds((gbyte*)gp, (sbyte*)lp, 16, 0, 0);
}

// ---------------- 1. weight-pool transpose to [d][o][i], f32 ----------------
__global__ __launch_bounds__(256) void k_wpoolT(const float* __restrict__ gwp,
                                                const float* __restrict__ uwp,
                                                float* __restrict__ wtg,
                                                float* __restrict__ wtu) {
  int idx = blockIdx.x * 256 + threadIdx.x;
  if (idx < 16 * 128 * 128) {
    int d = idx >> 14, rem = idx & 16383, o = rem >> 7, i = rem & 127;
    wtg[idx] = gwp[(d << 14) + (i << 7) + o];          // gwp[d][i][o]
  } else {
    int j = idx - 16 * 128 * 128;
    if (j < 16 * 64 * 128) {
      int d = j >> 13, rem = j & 8191, o = rem >> 7, i = rem & 127;
      wtu[j] = uwp[(d << 13) + (i << 6) + o];          // uwp[d][i][o(64)]
    }
  }
}

// ---------------- 2. supports = softmax(relu(E E^T)) row-wise, f16 ----------
__global__ __launch_bounds__(256) void k_supports(const float* __restrict__ emb,
                                                  _Float16* __restrict__ S) {
  int n = blockIdx.x, tid = threadIdx.x;
  float en[16];
#pragma unroll
  for (int d = 0; d < 16; d++) en[d] = emb[n * 16 + d];
  float v[16];
  float sum = 0.f;
#pragma unroll
  for (int i = 0; i < 16; i++) {
    int m = i * 256 + tid;
    const float* em = emb + m * 16;
    float acc = 0.f;
#pragma unroll
    for (int d = 0; d < 16; d++) acc += en[d] * em[d];
    acc = fmaxf(acc, 0.f);
    float e = __expf(acc);
    v[i] = e;
    sum += e;
  }
#pragma unroll
  for (int off = 32; off > 0; off >>= 1) sum += __shfl_down(sum, off);
  __shared__ float red[4];
  if ((tid & 63) == 0) red[tid >> 6] = sum;
  __syncthreads();
  float inv = 1.f / (red[0] + red[1] + red[2] + red[3]);
#pragma unroll
  for (int i = 0; i < 16; i++) S[n * 4096 + i * 256 + tid] = (_Float16)(v[i] * inv);
}

// ------- 3. xs_t[b][c][m] = f16(concat(x,state))  (c-major for GEMM B) ------
__global__ __launch_bounds__(256) void k_concat(const float* __restrict__ x,
                                                const float* __restrict__ st,
                                                _Float16* __restrict__ xs_t) {
  int m0 = blockIdx.x * 64, b = blockIdx.y, tid = threadIdx.x;
  __shared__ __attribute__((aligned(16))) _Float16 T[64][130];
#pragma unroll
  for (int i = 0; i < 16; i++) {
    int li = i * 256 + tid;
    int ml = li >> 6, c = li & 63;
    int base = (b * 4096 + m0 + ml) * 64 + c;
    T[ml][c] = (_Float16)x[base];
    T[ml][64 + c] = (_Float16)st[base];
  }
  __syncthreads();
  int cg = tid >> 3, mch = tid & 7;
#pragma unroll
  for (int cb = 0; cb < 4; cb++) {
    int c = cb * 32 + cg;
    f16x8 tmp;
#pragma unroll
    for (int j = 0; j < 8; j++) tmp[j] = T[mch * 8 + j][c];
    *reinterpret_cast<f16x8*>(&xs_t[(b * 128 + c) * 4096 + m0 + mch * 8]) = tmp;
  }
}

// -------- 4. Y[b][n][c] = sum_m S[n][m] * xs_t[b][c][m]  (f16 MFMA) ---------
__global__ __launch_bounds__(256) void k_gemm(const _Float16* __restrict__ S,
                                              const _Float16* __restrict__ Xt,
                                              _Float16* __restrict__ Y) {
  int nt = blockIdx.x, b = blockIdx.y;
  int tid = threadIdx.x, lane = tid & 63, w = tid >> 6;
  int wr = w >> 1, wc = w & 1;
  __shared__ __attribute__((aligned(16))) _Float16 As[128 * 64];
  __shared__ __attribute__((aligned(16))) _Float16 Bs[128 * 64];
  const _Float16* Sb = S + nt * 128 * 4096;
  const _Float16* Xb = Xt + b * 128 * 4096;
  f32x4 acc[4][4];
#pragma unroll
  for (int m = 0; m < 4; m++)
#pragma unroll
    for (int n = 0; n < 4; n++) acc[m][n] = (f32x4){0.f, 0.f, 0.f, 0.f};

  int lrow = lane >> 3;
  int lcol = (lane & 7) * 8;
  for (int k0 = 0; k0 < 4096; k0 += 64) {
    __syncthreads();
#pragma unroll
    for (int i = 0; i < 4; i++) {
      int j = w * 4 + i;
      int row = j * 8 + lrow;
      gload_lds16(Sb + row * 4096 + k0 + lcol, &As[j * 512]);
      gload_lds16(Xb + row * 4096 + k0 + lcol, &Bs[j * 512]);
    }
    __syncthreads();
#pragma unroll
    for (int kk = 0; kk < 2; kk++) {
      f16x8 af[4], bfr[4];
#pragma unroll
      for (int m = 0; m < 4; m++)
        af[m] = *reinterpret_cast<const f16x8*>(
            &As[(wr * 64 + m * 16 + (lane & 15)) * 64 + kk * 32 + (lane >> 4) * 8]);
#pragma unroll
      for (int n = 0; n < 4; n++)
        bfr[n] = *reinterpret_cast<const f16x8*>(
            &Bs[(wc * 64 + n * 16 + (lane & 15)) * 64 + kk * 32 + (lane >> 4) * 8]);
#pragma unroll
      for (int m = 0; m < 4; m++)
#pragma unroll
        for (int n = 0; n < 4; n++)
          acc[m][n] = __builtin_amdgcn_mfma_f32_16x16x32_f16(af[m], bfr[n], acc[m][n], 0, 0, 0);
    }
  }
  int r0 = (lane >> 4) * 4, cl = lane & 15;
#pragma unroll
  for (int m = 0; m < 4; m++)
#pragma unroll
    for (int r = 0; r < 4; r++) {
      int row = nt * 128 + wr * 64 + m * 16 + r0 + r;
#pragma unroll
      for (int n = 0; n < 4; n++) {
        int c = wc * 64 + n * 16 + cl;
        Y[(b * 4096 + row) * 128 + c] = (_Float16)acc[m][n][r];
      }
    }
}

// -------- 5. gate DIAGNOSTIC: MFMA vs VALU; mismatch -> NaN sentinel --------
__global__ __launch_bounds__(256) void k_gate(const _Float16* __restrict__ xg,  // [b][n][128]
                                              const float* __restrict__ emb,
                                              const float* __restrict__ wtg,    // [16][128][128]
                                              const float* __restrict__ gbp,    // [16][128]
                                              _Float16* __restrict__ zb,        // [n][b][64]
                                              _Float16* __restrict__ rb) {      // [n][b][64]
  int n = blockIdx.x, tid = threadIdx.x, lane = tid & 63, w = tid >> 6;
  __shared__ __attribute__((aligned(16))) _Float16 A[64][136];
  __shared__ __attribute__((aligned(16))) _Float16 W[128][136];
  __shared__ float ref_sh[64][128];
  __shared__ float bias_sh[128];
  __shared__ float e_sh[16];
  if (tid < 16) e_sh[tid] = emb[n * 16 + tid];
  __syncthreads();
  // stage A
  {
    int b = tid >> 2, i0 = (tid & 3) * 32;
    const f16x8* s8 = reinterpret_cast<const f16x8*>(xg + (b * 4096 + n) * 128 + i0);
#pragma unroll
    for (int c = 0; c < 4; c++)
      *reinterpret_cast<f16x8*>(&A[b][i0 + c * 8]) = s8[c];
  }
  // stage W
  {
    int o = tid >> 1, ih = tid & 1;
#pragma unroll
    for (int c8 = 0; c8 < 8; c8++) {
      int i0 = ih * 64 + c8 * 8;
      f32x4 a0 = {0.f, 0.f, 0.f, 0.f}, a1 = {0.f, 0.f, 0.f, 0.f};
#pragma unroll
      for (int d = 0; d < 16; d++) {
        float e = e_sh[d];
        const f32x4* p = reinterpret_cast<const f32x4*>(&wtg[(d * 128 + o) * 128 + i0]);
        a0 += e * p[0];
        a1 += e * p[1];
      }
      f16x8 pk;
#pragma unroll
      for (int q = 0; q < 4; q++) { pk[q] = (_Float16)a0[q]; pk[4 + q] = (_Float16)a1[q]; }
      *reinterpret_cast<f16x8*>(&W[o][i0]) = pk;
    }
  }
  if (tid < 128) {
    float s = 0.f;
#pragma unroll
    for (int d = 0; d < 16; d++) s += e_sh[d] * gbp[d * 128 + tid];
    bias_sh[tid] = s;
  }
  __syncthreads();
  // --- VALU reference pass (R3's proven compute): batch=lane, o = w*32+oi ---
  {
    float acc[32];
#pragma unroll
    for (int oi = 0; oi < 32; oi++) acc[oi] = bias_sh[w * 32 + oi];
    for (int i = 0; i < 128; i += 2) {
      f16x2 a2 = *reinterpret_cast<const f16x2*>(&A[lane][i]);
      float a0 = (float)a2[0], a1 = (float)a2[1];
#pragma unroll
      for (int oi = 0; oi < 32; oi++) {
        f16x2 w2 = *reinterpret_cast<const f16x2*>(&W[w * 32 + oi][i]);
        acc[oi] += a0 * (float)w2[0] + a1 * (float)w2[1];
      }
    }
#pragma unroll
    for (int oi = 0; oi < 32; oi++) ref_sh[lane][w * 32 + oi] = acc[oi];
  }
  __syncthreads();
  // --- MFMA pass (R4's compute) ---
  f32x4 acc[4][2];
#pragma unroll
  for (int m = 0; m < 4; m++)
#pragma unroll
    for (int n2 = 0; n2 < 2; n2++) acc[m][n2] = (f32x4){0.f, 0.f, 0.f, 0.f};
#pragma unroll
  for (int kk = 0; kk < 4; kk++) {
    int colh = kk * 32 + (lane >> 4) * 8;
    f16x8 af[4], bf[2];
#pragma unroll
    for (int m = 0; m < 4; m++)
      af[m] = *reinterpret_cast<const f16x8*>(&A[m * 16 + (lane & 15)][colh]);
#pragma unroll
    for (int n2 = 0; n2 < 2; n2++)
      bf[n2] = *reinterpret_cast<const f16x8*>(&W[w * 32 + n2 * 16 + (lane & 15)][colh]);
#pragma unroll
    for (int m = 0; m < 4; m++)
#pragma unroll
      for (int n2 = 0; n2 < 2; n2++)
        acc[m][n2] = __builtin_amdgcn_mfma_f32_16x16x32_f16(af[m], bf[n2], acc[m][n2], 0, 0, 0);
  }
  int r0 = (lane >> 4) * 4, cl = lane & 15;
#pragma unroll
  for (int m = 0; m < 4; m++)
#pragma unroll
    for (int n2 = 0; n2 < 2; n2++) {
      int o = w * 32 + n2 * 16 + cl;
#pragma unroll
      for (int r = 0; r < 4; r++) {
        int bb = m * 16 + r0 + r;
        float val = acc[m][n2][r] + bias_sh[o];
        float ref = ref_sh[bb][o];
        float res;
        if (fabsf(val - ref) > 0.01f) res = __builtin_nanf("");   // gate-MFMA bug
        else res = 1.f / (1.f + __expf(-val));
        if (o < 64) zb[(n * 64 + bb) * 64 + o] = (_Float16)res;
        else        rb[(n * 64 + bb) * 64 + (o - 64)] = (_Float16)res;
      }
    }
}

// ------------- 6. xs_t[b][64+o][m] = f16(z[m][b][o] * state[b][m][o]) -------
__global__ __launch_bounds__(256) void k_cand(const _Float16* __restrict__ zb,
                                              const float* __restrict__ st,
                                              _Float16* __restrict__ xs_t) {
  int m0 = blockIdx.x * 64, b = blockIdx.y, tid = threadIdx.x;
  __shared__ __attribute__((aligned(16))) _Float16 T[64][66];
#pragma unroll
  for (int i = 0; i < 16; i++) {
    int li = i * 256 + tid, ml = li >> 6, o = li & 63;
    float z = (float)zb[((m0 + ml) * 64 + b) * 64 + o];
    float s = st[(b * 4096 + m0 + ml) * 64 + o];
    T[ml][o] = (_Float16)(z * s);
  }
  __syncthreads();
  int og = tid >> 3, mch = tid & 7;
#pragma unroll
  for (int cb = 0; cb < 2; cb++) {
    int o = cb * 32 + og;
    f16x8 tmp;
#pragma unroll
    for (int j = 0; j < 8; j++) tmp[j] = T[mch * 8 + j][o];
    *reinterpret_cast<f16x8*>(&xs_t[(b * 128 + 64 + o) * 4096 + m0 + mch * 8]) = tmp;
  }
}

// ---- 7. update DIAGNOSTIC: MFMA vs VALU; mismatch -> 500.0 sentinel --------
__global__ __launch_bounds__(256) void k_upd(const _Float16* __restrict__ xg2,  // [b][n][128]
                                             const float* __restrict__ emb,
                                             const float* __restrict__ wtu,    // [16][64][128]
                                             const float* __restrict__ ubp,    // [16][64]
                                             const _Float16* __restrict__ rb,  // [n][b][64]
                                             const float* __restrict__ st,
                                             float* __restrict__ out) {
  int n = blockIdx.x, tid = threadIdx.x, lane = tid & 63, w = tid >> 6;
  __shared__ __attribute__((aligned(16))) _Float16 A[64][136];
  __shared__ __attribute__((aligned(16))) _Float16 W[64][136];
  __shared__ float ref_sh[64][64];
  __shared__ float bias_sh[64];
  __shared__ float e_sh[16];
  if (tid < 16) e_sh[tid] = emb[n * 16 + tid];
  __syncthreads();
  // stage A
  {
    int b = tid >> 2, i0 = (tid & 3) * 32;
    const f16x8* s8 = reinterpret_cast<const f16x8*>(xg2 + (b * 4096 + n) * 128 + i0);
#pragma unroll
    for (int c = 0; c < 4; c++)
      *reinterpret_cast<f16x8*>(&A[b][i0 + c * 8]) = s8[c];
  }
  // stage W
  {
    int o = tid >> 2, q = tid & 3;
#pragma unroll
    for (int c8 = 0; c8 < 4; c8++) {
      int i0 = q * 32 + c8 * 8;
      f32x4 a0 = {0.f, 0.f, 0.f, 0.f}, a1 = {0.f, 0.f, 0.f, 0.f};
#pragma unroll
      for (int d = 0; d < 16; d++) {
        float e = e_sh[d];
        const f32x4* p = reinterpret_cast<const f32x4*>(&wtu[(d * 64 + o) * 128 + i0]);
        a0 += e * p[0];
        a1 += e * p[1];
      }
      f16x8 pk;
#pragma unroll
      for (int q2 = 0; q2 < 4; q2++) { pk[q2] = (_Float16)a0[q2]; pk[4 + q2] = (_Float16)a1[q2]; }
      *reinterpret_cast<f16x8*>(&W[o][i0]) = pk;
    }
  }
  if (tid < 64) {
    float s = 0.f;
#pragma unroll
    for (int d = 0; d < 16; d++) s += e_sh[d] * ubp[d * 64 + tid];
    bias_sh[tid] = s;
  }
  __syncthreads();
  // --- VALU reference pass (R3's proven compute): batch=lane, o = w*16+oi ---
  {
    float acc[16];
#pragma unroll
    for (int oi = 0; oi < 16; oi++) acc[oi] = bias_sh[w * 16 + oi];
    for (int i = 0; i < 128; i += 2) {
      f16x2 a2 = *reinterpret_cast<const f16x2*>(&A[lane][i]);
      float a0 = (float)a2[0], a1 = (float)a2[1];
#pragma unroll
      for (int oi = 0; oi < 16; oi++) {
        f16x2 w2 = *reinterpret_cast<const f16x2*>(&W[w * 16 + oi][i]);
        acc[oi] += a0 * (float)w2[0] + a1 * (float)w2[1];
      }
    }
#pragma unroll
    for (int oi = 0; oi < 16; oi++) ref_sh[lane][w * 16 + oi] = acc[oi];
  }
  __syncthreads();
  // --- MFMA pass (R4's compute) ---
  f32x4 acc[4];
#pragma unroll
  for (int m = 0; m < 4; m++) acc[m] = (f32x4){0.f, 0.f, 0.f, 0.f};
#pragma unroll
  for (int kk = 0; kk < 4; kk++) {
    int colh = kk * 32 + (lane >> 4) * 8;
    f16x8 bf = *reinterpret_cast<const f16x8*>(&W[w * 16 + (lane & 15)][colh]);
#pragma unroll
    for (int m = 0; m < 4; m++) {
      f16x8 af = *reinterpret_cast<const f16x8*>(&A[m * 16 + (lane & 15)][colh]);
      acc[m] = __builtin_amdgcn_mfma_f32_16x16x32_f16(af, bf, acc[m], 0, 0, 0);
    }
  }
  int r0 = (lane >> 4) * 4, cl = lane & 15, o = w * 16 + cl;
  float bias = bias_sh[o];
#pragma unroll
  for (int m = 0; m < 4; m++)
#pragma unroll
    for (int r = 0; r < 4; r++) {
      int bb = m * 16 + r0 + r;
      float val = acc[m][r] + bias;
      float ref = ref_sh[bb][o];
      float outv;
      if (val != val || ref != ref) {
        outv = __builtin_nanf("");            // NaN from gate bug propagates
      } else if (fabsf(val - ref) > 0.01f) {
        outv = 500.0f;                        // upd-MFMA bug signature
      } else {
        float e2 = __expf(2.f * val);
        float hc = 1.f - 2.f / (e2 + 1.f);    // tanh
        float rr = (float)rb[(n * 64 + bb) * 64 + o];
        float s = st[(bb * 4096 + n) * 64 + o];
        outv = rr * s + (1.f - rr) * hc;
      }
      out[(bb * 4096 + n) * 64 + o] = outv;
    }
}

extern "C" void kernel_launch(void* const* d_in, const int* in_sizes, int n_in,
                              void* d_out, int out_size, void* d_ws, size_t ws_size,
                              hipStream_t stream) {
  const float* x   = (const float*)d_in[0];
  const float* st  = (const float*)d_in[1];
  const float* emb = (const float*)d_in[2];
  const float* gwp = (const float*)d_in[3];
  const float* gbp = (const float*)d_in[4];
  const float* uwp = (const float*)d_in[5];
  const float* ubp = (const float*)d_in[6];
  float* out = (float*)d_out;
  char* ws = (char*)d_ws;

  _Float16* S    = (_Float16*)(ws + 0);          // 33.5 MB
  _Float16* xs_t = (_Float16*)(ws + 33554432);   // 67 MB [b][c][m]
  _Float16* xg   = (_Float16*)(ws + 100663296);  // 67 MB
  _Float16* zb   = (_Float16*)(ws + 167772160);  // 33.5 MB [n][b][64]
  _Float16* rb   = (_Float16*)(ws + 201326592);  // 33.5 MB [n][b][64]
  float* wtg = (float*)(ws + 234881024);         // 1 MB
  float* wtu = (float*)(ws + 235929600);         // 0.5 MB
  if (ws_size < 236453888ull) return;

  k_wpoolT<<<1536, 256, 0, stream>>>(gwp, uwp, wtg, wtu);
  k_supports<<<4096, 256, 0, stream>>>(emb, S);
  k_concat<<<dim3(64, 64), 256, 0, stream>>>(x, st, xs_t);
  k_gemm<<<dim3(32, 64), 256, 0, stream>>>(S, xs_t, xg);
  k_gate<<<4096, 256, 0, stream>>>(xg, emb, wtg, gbp, zb, rb);
  k_cand<<<dim3(64, 64), 256, 0, stream>>>(zb, st, xs_t);
  k_gemm<<<dim3(32, 64), 256, 0, stream>>>(S, xs_t, xg);
  k_upd<<<4096, 256, 0, stream>>>(xg, emb, wtu, ubp, rb, st, out);
}

// Round 6
// 2045.205 us; speedup vs baseline: 1.2120x; 1.2120x over previous
//
#include <hip/hip_runtime.h>

typedef float f32x4 __attribute__((ext_vector_type(4)));
typedef _Float16 f16x8 __attribute__((ext_vector_type(8)));

typedef __attribute__((address_space(1))) const unsigned char gbyte;
typedef __attribute__((address_space(3))) unsigned char sbyte;
__device__ __forceinline__ void gload_lds16(const void* gp, void* lp) {
  __builtin_amdgcn_global_load_lds((gbyte*)gp, (sbyte*)lp, 16, 0, 0);
}

// ---------------- 1. weight-pool transpose to [d][o][i], f32 ----------------
__global__ __launch_bounds__(256) void k_wpoolT(const float* __restrict__ gwp,
                                                const float* __restrict__ uwp,
                                                float* __restrict__ wtg,
                                                float* __restrict__ wtu) {
  int idx = blockIdx.x * 256 + threadIdx.x;
  if (idx < 16 * 128 * 128) {
    int d = idx >> 14, rem = idx & 16383, o = rem >> 7, i = rem & 127;
    wtg[idx] = gwp[(d << 14) + (i << 7) + o];          // gwp[d][i][o]
  } else {
    int j = idx - 16 * 128 * 128;
    if (j < 16 * 64 * 128) {
      int d = j >> 13, rem = j & 8191, o = rem >> 7, i = rem & 127;
      wtu[j] = uwp[(d << 13) + (i << 6) + o];          // uwp[d][i][o(64)]
    }
  }
}

// ---------------- 2. supports = softmax(relu(E E^T)) row-wise, f16 ----------
__global__ __launch_bounds__(256) void k_supports(const float* __restrict__ emb,
                                                  _Float16* __restrict__ S) {
  int n = blockIdx.x, tid = threadIdx.x;
  float en[16];
#pragma unroll
  for (int d = 0; d < 16; d++) en[d] = emb[n * 16 + d];
  float v[16];
  float sum = 0.f;
#pragma unroll
  for (int i = 0; i < 16; i++) {
    int m = i * 256 + tid;
    const float* em = emb + m * 16;
    float acc = 0.f;
#pragma unroll
    for (int d = 0; d < 16; d++) acc += en[d] * em[d];
    acc = fmaxf(acc, 0.f);
    float e = __expf(acc);
    v[i] = e;
    sum += e;
  }
#pragma unroll
  for (int off = 32; off > 0; off >>= 1) sum += __shfl_down(sum, off);
  __shared__ float red[4];
  if ((tid & 63) == 0) red[tid >> 6] = sum;
  __syncthreads();
  float inv = 1.f / (red[0] + red[1] + red[2] + red[3]);
#pragma unroll
  for (int i = 0; i < 16; i++) S[n * 4096 + i * 256 + tid] = (_Float16)(v[i] * inv);
}

// ------- 3. xs_t[b][c][m] = f16(concat(x,state))  (c-major for GEMM B) ------
__global__ __launch_bounds__(256) void k_concat(const float* __restrict__ x,
                                                const float* __restrict__ st,
                                                _Float16* __restrict__ xs_t) {
  int m0 = blockIdx.x * 64, b = blockIdx.y, tid = threadIdx.x;
  __shared__ __attribute__((aligned(16))) _Float16 T[64][130];
#pragma unroll
  for (int i = 0; i < 16; i++) {
    int li = i * 256 + tid;
    int ml = li >> 6, c = li & 63;
    int base = (b * 4096 + m0 + ml) * 64 + c;
    T[ml][c] = (_Float16)x[base];
    T[ml][64 + c] = (_Float16)st[base];
  }
  __syncthreads();
  int cg = tid >> 3, mch = tid & 7;
#pragma unroll
  for (int cb = 0; cb < 4; cb++) {
    int c = cb * 32 + cg;
    f16x8 tmp;
#pragma unroll
    for (int j = 0; j < 8; j++) tmp[j] = T[mch * 8 + j][c];
    *reinterpret_cast<f16x8*>(&xs_t[(b * 128 + c) * 4096 + m0 + mch * 8]) = tmp;
  }
}

// -------- 4. Y[b][n][c] = sum_m S[n][m] * xs_t[b][c][m]  (f16 MFMA) ---------
__global__ __launch_bounds__(256) void k_gemm(const _Float16* __restrict__ S,
                                              const _Float16* __restrict__ Xt,
                                              _Float16* __restrict__ Y) {
  int nt = blockIdx.x, b = blockIdx.y;
  int tid = threadIdx.x, lane = tid & 63, w = tid >> 6;
  int wr = w >> 1, wc = w & 1;
  __shared__ __attribute__((aligned(16))) _Float16 As[128 * 64];
  __shared__ __attribute__((aligned(16))) _Float16 Bs[128 * 64];
  const _Float16* Sb = S + nt * 128 * 4096;
  const _Float16* Xb = Xt + b * 128 * 4096;
  f32x4 acc[4][4];
#pragma unroll
  for (int m = 0; m < 4; m++)
#pragma unroll
    for (int n = 0; n < 4; n++) acc[m][n] = (f32x4){0.f, 0.f, 0.f, 0.f};

  int lrow = lane >> 3;
  int lcol = (lane & 7) * 8;
  for (int k0 = 0; k0 < 4096; k0 += 64) {
    __syncthreads();
#pragma unroll
    for (int i = 0; i < 4; i++) {
      int j = w * 4 + i;
      int row = j * 8 + lrow;
      gload_lds16(Sb + row * 4096 + k0 + lcol, &As[j * 512]);
      gload_lds16(Xb + row * 4096 + k0 + lcol, &Bs[j * 512]);
    }
    __syncthreads();
#pragma unroll
    for (int kk = 0; kk < 2; kk++) {
      f16x8 af[4], bfr[4];
#pragma unroll
      for (int m = 0; m < 4; m++)
        af[m] = *reinterpret_cast<const f16x8*>(
            &As[(wr * 64 + m * 16 + (lane & 15)) * 64 + kk * 32 + (lane >> 4) * 8]);
#pragma unroll
      for (int n = 0; n < 4; n++)
        bfr[n] = *reinterpret_cast<const f16x8*>(
            &Bs[(wc * 64 + n * 16 + (lane & 15)) * 64 + kk * 32 + (lane >> 4) * 8]);
#pragma unroll
      for (int m = 0; m < 4; m++)
#pragma unroll
        for (int n = 0; n < 4; n++)
          acc[m][n] = __builtin_amdgcn_mfma_f32_16x16x32_f16(af[m], bfr[n], acc[m][n], 0, 0, 0);
    }
  }
  int r0 = (lane >> 4) * 4, cl = lane & 15;
#pragma unroll
  for (int m = 0; m < 4; m++)
#pragma unroll
    for (int r = 0; r < 4; r++) {
      int row = nt * 128 + wr * 64 + m * 16 + r0 + r;
#pragma unroll
      for (int n = 0; n < 4; n++) {
        int c = wc * 64 + n * 16 + cl;
        Y[(b * 4096 + row) * 128 + c] = (_Float16)acc[m][n][r];
      }
    }
}

// ---- 5. gate (register-blocked VALU): z_r = sigmoid(x_g @ W_n + b_n) -------
// Numerics identical to R3's passing VALU kernel (f16 A, W rounded once from
// f32 combine, sequential-i f32 accumulation). Each thread: 4 batches x 8 outs,
// f16x8 LDS reads (192 ds_read_b128 per thread vs R3's 2112 scalar reads).
__global__ __launch_bounds__(256) void k_gate(const _Float16* __restrict__ xg,  // [b][n][128]
                                              const float* __restrict__ emb,
                                              const float* __restrict__ wtg,    // [16][128][128]
                                              const float* __restrict__ gbp,    // [16][128]
                                              _Float16* __restrict__ zb,        // [n][b][64]
                                              _Float16* __restrict__ rb) {      // [n][b][64]
  int n = blockIdx.x, tid = threadIdx.x;
  __shared__ __attribute__((aligned(16))) _Float16 A[64][136];
  __shared__ __attribute__((aligned(16))) _Float16 W[128][136];
  __shared__ float bias_sh[128];
  __shared__ float e_sh[16];
  if (tid < 16) e_sh[tid] = emb[n * 16 + tid];
  __syncthreads();
  // stage A (vector form proven in R5)
  {
    int b = tid >> 2, i0 = (tid & 3) * 32;
    const f16x8* s8 = reinterpret_cast<const f16x8*>(xg + (b * 4096 + n) * 128 + i0);
#pragma unroll
    for (int c = 0; c < 4; c++)
      *reinterpret_cast<f16x8*>(&A[b][i0 + c * 8]) = s8[c];
  }
  // stage W: W[o][i] = sum_d e_d * wtg[d][o][i] (f32 acc -> f16 once)
  {
    int o = tid >> 1, ih = tid & 1;
#pragma unroll
    for (int c8 = 0; c8 < 8; c8++) {
      int i0 = ih * 64 + c8 * 8;
      f32x4 a0 = {0.f, 0.f, 0.f, 0.f}, a1 = {0.f, 0.f, 0.f, 0.f};
#pragma unroll
      for (int d = 0; d < 16; d++) {
        float e = e_sh[d];
        const f32x4* p = reinterpret_cast<const f32x4*>(&wtg[(d * 128 + o) * 128 + i0]);
        a0 += e * p[0];
        a1 += e * p[1];
      }
      f16x8 pk;
#pragma unroll
      for (int q = 0; q < 4; q++) { pk[q] = (_Float16)a0[q]; pk[4 + q] = (_Float16)a1[q]; }
      *reinterpret_cast<f16x8*>(&W[o][i0]) = pk;
    }
  }
  if (tid < 128) {
    float s = 0.f;
#pragma unroll
    for (int d = 0; d < 16; d++) s += e_sh[d] * gbp[d * 128 + tid];
    bias_sh[tid] = s;
  }
  __syncthreads();
  // compute: b0 = (tid&15)*4 (4 batches), o0 = (tid>>4)*8 (8 outputs)
  int b0 = (tid & 15) * 4, o0 = (tid >> 4) * 8;
  float acc[4][8];
#pragma unroll
  for (int j = 0; j < 4; j++)
#pragma unroll
    for (int k = 0; k < 8; k++) acc[j][k] = bias_sh[o0 + k];
#pragma unroll
  for (int is = 0; is < 128; is += 8) {
    f16x8 av[4], wv[8];
#pragma unroll
    for (int j = 0; j < 4; j++) av[j] = *reinterpret_cast<const f16x8*>(&A[b0 + j][is]);
#pragma unroll
    for (int k = 0; k < 8; k++) wv[k] = *reinterpret_cast<const f16x8*>(&W[o0 + k][is]);
#pragma unroll
    for (int j = 0; j < 4; j++)
#pragma unroll
      for (int k = 0; k < 8; k++)
#pragma unroll
        for (int q = 0; q < 8; q++)
          acc[j][k] += (float)av[j][q] * (float)wv[k][q];
  }
#pragma unroll
  for (int j = 0; j < 4; j++) {
    int b = b0 + j;
    f16x8 pk;
#pragma unroll
    for (int k = 0; k < 8; k++) pk[k] = (_Float16)(1.f / (1.f + __expf(-acc[j][k])));
    if (o0 < 64) *reinterpret_cast<f16x8*>(&zb[(n * 64 + b) * 64 + o0]) = pk;
    else         *reinterpret_cast<f16x8*>(&rb[(n * 64 + b) * 64 + (o0 - 64)]) = pk;
  }
}

// ------------- 6. xs_t[b][64+o][m] = f16(z[m][b][o] * state[b][m][o]) -------
__global__ __launch_bounds__(256) void k_cand(const _Float16* __restrict__ zb,
                                              const float* __restrict__ st,
                                              _Float16* __restrict__ xs_t) {
  int m0 = blockIdx.x * 64, b = blockIdx.y, tid = threadIdx.x;
  __shared__ __attribute__((aligned(16))) _Float16 T[64][66];
#pragma unroll
  for (int i = 0; i < 16; i++) {
    int li = i * 256 + tid, ml = li >> 6, o = li & 63;
    float z = (float)zb[((m0 + ml) * 64 + b) * 64 + o];
    float s = st[(b * 4096 + m0 + ml) * 64 + o];
    T[ml][o] = (_Float16)(z * s);
  }
  __syncthreads();
  int og = tid >> 3, mch = tid & 7;
#pragma unroll
  for (int cb = 0; cb < 2; cb++) {
    int o = cb * 32 + og;
    f16x8 tmp;
#pragma unroll
    for (int j = 0; j < 8; j++) tmp[j] = T[mch * 8 + j][o];
    *reinterpret_cast<f16x8*>(&xs_t[(b * 128 + 64 + o) * 4096 + m0 + mch * 8]) = tmp;
  }
}

// ---- 7. update (register-blocked VALU): hc=tanh(xg2 @ Wu_n + bu);
//      h = r*state + (1-r)*hc -> out.  4 batches x 4 outputs per thread. -----
__global__ __launch_bounds__(256) void k_upd(const _Float16* __restrict__ xg2,  // [b][n][128]
                                             const float* __restrict__ emb,
                                             const float* __restrict__ wtu,    // [16][64][128]
                                             const float* __restrict__ ubp,    // [16][64]
                                             const _Float16* __restrict__ rb,  // [n][b][64]
                                             const float* __restrict__ st,
                                             float* __restrict__ out) {
  int n = blockIdx.x, tid = threadIdx.x;
  __shared__ __attribute__((aligned(16))) _Float16 A[64][136];
  __shared__ __attribute__((aligned(16))) _Float16 W[64][136];
  __shared__ float bias_sh[64];
  __shared__ float e_sh[16];
  if (tid < 16) e_sh[tid] = emb[n * 16 + tid];
  __syncthreads();
  // stage A
  {
    int b = tid >> 2, i0 = (tid & 3) * 32;
    const f16x8* s8 = reinterpret_cast<const f16x8*>(xg2 + (b * 4096 + n) * 128 + i0);
#pragma unroll
    for (int c = 0; c < 4; c++)
      *reinterpret_cast<f16x8*>(&A[b][i0 + c * 8]) = s8[c];
  }
  // stage W
  {
    int o = tid >> 2, q = tid & 3;
#pragma unroll
    for (int c8 = 0; c8 < 4; c8++) {
      int i0 = q * 32 + c8 * 8;
      f32x4 a0 = {0.f, 0.f, 0.f, 0.f}, a1 = {0.f, 0.f, 0.f, 0.f};
#pragma unroll
      for (int d = 0; d < 16; d++) {
        float e = e_sh[d];
        const f32x4* p = reinterpret_cast<const f32x4*>(&wtu[(d * 64 + o) * 128 + i0]);
        a0 += e * p[0];
        a1 += e * p[1];
      }
      f16x8 pk;
#pragma unroll
      for (int q2 = 0; q2 < 4; q2++) { pk[q2] = (_Float16)a0[q2]; pk[4 + q2] = (_Float16)a1[q2]; }
      *reinterpret_cast<f16x8*>(&W[o][i0]) = pk;
    }
  }
  if (tid < 64) {
    float s = 0.f;
#pragma unroll
    for (int d = 0; d < 16; d++) s += e_sh[d] * ubp[d * 64 + tid];
    bias_sh[tid] = s;
  }
  __syncthreads();
  // compute: b0 = (tid&15)*4 (4 batches), o0 = (tid>>4)*4 (4 outputs)
  int b0 = (tid & 15) * 4, o0 = (tid >> 4) * 4;
  float acc[4][4];
#pragma unroll
  for (int j = 0; j < 4; j++)
#pragma unroll
    for (int k = 0; k < 4; k++) acc[j][k] = bias_sh[o0 + k];
#pragma unroll
  for (int is = 0; is < 128; is += 8) {
    f16x8 av[4], wv[4];
#pragma unroll
    for (int j = 0; j < 4; j++) av[j] = *reinterpret_cast<const f16x8*>(&A[b0 + j][is]);
#pragma unroll
    for (int k = 0; k < 4; k++) wv[k] = *reinterpret_cast<const f16x8*>(&W[o0 + k][is]);
#pragma unroll
    for (int j = 0; j < 4; j++)
#pragma unroll
      for (int k = 0; k < 4; k++)
#pragma unroll
        for (int q = 0; q < 8; q++)
          acc[j][k] += (float)av[j][q] * (float)wv[k][q];
  }
#pragma unroll
  for (int j = 0; j < 4; j++) {
    int b = b0 + j;
    const f32x4 s4 = *reinterpret_cast<const f32x4*>(&st[(b * 4096 + n) * 64 + o0]);
    f32x4 o4;
#pragma unroll
    for (int k = 0; k < 4; k++) {
      float e2 = __expf(2.f * acc[j][k]);
      float hc = 1.f - 2.f / (e2 + 1.f);     // tanh
      float rr = (float)rb[(n * 64 + b) * 64 + o0 + k];
      o4[k] = rr * s4[k] + (1.f - rr) * hc;
    }
    *reinterpret_cast<f32x4*>(&out[(b * 4096 + n) * 64 + o0]) = o4;
  }
}

extern "C" void kernel_launch(void* const* d_in, const int* in_sizes, int n_in,
                              void* d_out, int out_size, void* d_ws, size_t ws_size,
                              hipStream_t stream) {
  const float* x   = (const float*)d_in[0];
  const float* st  = (const float*)d_in[1];
  const float* emb = (const float*)d_in[2];
  const float* gwp = (const float*)d_in[3];
  const float* gbp = (const float*)d_in[4];
  const float* uwp = (const float*)d_in[5];
  const float* ubp = (const float*)d_in[6];
  float* out = (float*)d_out;
  char* ws = (char*)d_ws;

  _Float16* S    = (_Float16*)(ws + 0);          // 33.5 MB (alive throughout)
  _Float16* xs_t = (_Float16*)(ws + 33554432);   // 67 MB [b][c][m]
  _Float16* xg   = (_Float16*)(ws + 100663296);  // 67 MB (gemm1 out; gemm2 overwrites)
  _Float16* zb   = (_Float16*)(ws + 167772160);  // 33.5 MB [n][b][64]
  _Float16* rb   = (_Float16*)(ws + 201326592);  // 33.5 MB [n][b][64]
  float* wtg = (float*)(ws + 234881024);         // 1 MB
  float* wtu = (float*)(ws + 235929600);         // 0.5 MB
  if (ws_size < 236453888ull) return;  // fail loudly rather than corrupt

  k_wpoolT<<<1536, 256, 0, stream>>>(gwp, uwp, wtg, wtu);
  k_supports<<<4096, 256, 0, stream>>>(emb, S);
  k_concat<<<dim3(64, 64), 256, 0, stream>>>(x, st, xs_t);
  k_gemm<<<dim3(32, 64), 256, 0, stream>>>(S, xs_t, xg);
  k_gate<<<4096, 256, 0, stream>>>(xg, emb, wtg, gbp, zb, rb);
  k_cand<<<dim3(64, 64), 256, 0, stream>>>(zb, st, xs_t);
  k_gemm<<<dim3(32, 64), 256, 0, stream>>>(S, xs_t, xg);
  k_upd<<<4096, 256, 0, stream>>>(xg, emb, wtu, ubp, rb, st, out);
}

// Round 7
// 1420.212 us; speedup vs baseline: 1.7453x; 1.4401x over previous
//
#include <hip/hip_runtime.h>

typedef float f32x4 __attribute__((ext_vector_type(4)));
typedef _Float16 f16x8 __attribute__((ext_vector_type(8)));
typedef _Float16 f16x4 __attribute__((ext_vector_type(4)));

typedef __attribute__((address_space(1))) const unsigned char gbyte;
typedef __attribute__((address_space(3))) unsigned char sbyte;
__device__ __forceinline__ void gload_lds16(const void* gp, void* lp) {
  __builtin_amdgcn_global_load_lds((gbyte*)gp, (sbyte*)lp, 16, 0, 0);
}

// ---------------- 1. weight-pool transpose to [d][o][i], f32 ----------------
__global__ __launch_bounds__(256) void k_wpoolT(const float* __restrict__ gwp,
                                                const float* __restrict__ uwp,
                                                float* __restrict__ wtg,
                                                float* __restrict__ wtu) {
  int idx = blockIdx.x * 256 + threadIdx.x;
  if (idx < 16 * 128 * 128) {
    int d = idx >> 14, rem = idx & 16383, o = rem >> 7, i = rem & 127;
    wtg[idx] = gwp[(d << 14) + (i << 7) + o];          // gwp[d][i][o]
  } else {
    int j = idx - 16 * 128 * 128;
    if (j < 16 * 64 * 128) {
      int d = j >> 13, rem = j & 8191, o = rem >> 7, i = rem & 127;
      wtu[j] = uwp[(d << 13) + (i << 6) + o];          // uwp[d][i][o(64)]
    }
  }
}

// ---------------- 2. supports = softmax(relu(E E^T)) row-wise, f16 ----------
__global__ __launch_bounds__(256) void k_supports(const float* __restrict__ emb,
                                                  _Float16* __restrict__ S) {
  int n = blockIdx.x, tid = threadIdx.x;
  float en[16];
#pragma unroll
  for (int d = 0; d < 16; d++) en[d] = emb[n * 16 + d];
  float v[16];
  float sum = 0.f;
#pragma unroll
  for (int i = 0; i < 16; i++) {
    int m = i * 256 + tid;
    const float* em = emb + m * 16;
    float acc = 0.f;
#pragma unroll
    for (int d = 0; d < 16; d++) acc += en[d] * em[d];
    acc = fmaxf(acc, 0.f);
    float e = __expf(acc);
    v[i] = e;
    sum += e;
  }
#pragma unroll
  for (int off = 32; off > 0; off >>= 1) sum += __shfl_down(sum, off);
  __shared__ float red[4];
  if ((tid & 63) == 0) red[tid >> 6] = sum;
  __syncthreads();
  float inv = 1.f / (red[0] + red[1] + red[2] + red[3]);
#pragma unroll
  for (int i = 0; i < 16; i++) S[n * 4096 + i * 256 + tid] = (_Float16)(v[i] * inv);
}

// ------- 3. xs_t[b][c][m] = f16(concat(x,state))  (c-major for GEMM B) ------
__global__ __launch_bounds__(256) void k_concat(const float* __restrict__ x,
                                                const float* __restrict__ st,
                                                _Float16* __restrict__ xs_t) {
  int m0 = blockIdx.x * 64, b = blockIdx.y, tid = threadIdx.x;
  __shared__ __attribute__((aligned(16))) _Float16 T[64][130];
#pragma unroll
  for (int i = 0; i < 16; i++) {
    int li = i * 256 + tid;
    int ml = li >> 6, c = li & 63;
    int base = (b * 4096 + m0 + ml) * 64 + c;
    T[ml][c] = (_Float16)x[base];
    T[ml][64 + c] = (_Float16)st[base];
  }
  __syncthreads();
  int cg = tid >> 3, mch = tid & 7;
#pragma unroll
  for (int cb = 0; cb < 4; cb++) {
    int c = cb * 32 + cg;
    f16x8 tmp;
#pragma unroll
    for (int j = 0; j < 8; j++) tmp[j] = T[mch * 8 + j][c];
    *reinterpret_cast<f16x8*>(&xs_t[(b * 128 + c) * 4096 + m0 + mch * 8]) = tmp;
  }
}

// -------- 4. Y[b][n][c] = sum_m S[n][m] * xs_t[b][c][m]  (f16 MFMA) ---------
__global__ __launch_bounds__(256) void k_gemm(const _Float16* __restrict__ S,
                                              const _Float16* __restrict__ Xt,
                                              _Float16* __restrict__ Y) {
  int nt = blockIdx.x, b = blockIdx.y;
  int tid = threadIdx.x, lane = tid & 63, w = tid >> 6;
  int wr = w >> 1, wc = w & 1;
  __shared__ __attribute__((aligned(16))) _Float16 As[128 * 64];
  __shared__ __attribute__((aligned(16))) _Float16 Bs[128 * 64];
  const _Float16* Sb = S + nt * 128 * 4096;
  const _Float16* Xb = Xt + b * 128 * 4096;
  f32x4 acc[4][4];
#pragma unroll
  for (int m = 0; m < 4; m++)
#pragma unroll
    for (int n = 0; n < 4; n++) acc[m][n] = (f32x4){0.f, 0.f, 0.f, 0.f};

  int lrow = lane >> 3;
  int lcol = (lane & 7) * 8;
  for (int k0 = 0; k0 < 4096; k0 += 64) {
    __syncthreads();
#pragma unroll
    for (int i = 0; i < 4; i++) {
      int j = w * 4 + i;
      int row = j * 8 + lrow;
      gload_lds16(Sb + row * 4096 + k0 + lcol, &As[j * 512]);
      gload_lds16(Xb + row * 4096 + k0 + lcol, &Bs[j * 512]);
    }
    __syncthreads();
#pragma unroll
    for (int kk = 0; kk < 2; kk++) {
      f16x8 af[4], bfr[4];
#pragma unroll
      for (int m = 0; m < 4; m++)
        af[m] = *reinterpret_cast<const f16x8*>(
            &As[(wr * 64 + m * 16 + (lane & 15)) * 64 + kk * 32 + (lane >> 4) * 8]);
#pragma unroll
      for (int n = 0; n < 4; n++)
        bfr[n] = *reinterpret_cast<const f16x8*>(
            &Bs[(wc * 64 + n * 16 + (lane & 15)) * 64 + kk * 32 + (lane >> 4) * 8]);
#pragma unroll
      for (int m = 0; m < 4; m++)
#pragma unroll
        for (int n = 0; n < 4; n++)
          acc[m][n] = __builtin_amdgcn_mfma_f32_16x16x32_f16(af[m], bfr[n], acc[m][n], 0, 0, 0);
    }
  }
  int r0 = (lane >> 4) * 4, cl = lane & 15;
#pragma unroll
  for (int m = 0; m < 4; m++)
#pragma unroll
    for (int r = 0; r < 4; r++) {
      int row = nt * 128 + wr * 64 + m * 16 + r0 + r;
#pragma unroll
      for (int n = 0; n < 4; n++) {
        int c = wc * 64 + n * 16 + cl;
        Y[(b * 4096 + row) * 128 + c] = (_Float16)acc[m][n][r];
      }
    }
}

// ---- 5a. k_wall: W_all[nn][o*i] = f16( sum_d E[n0+nn][d] * wt[d][o*i] ) ----
// Register-blocked combine: block = 64 nodes x 2048-elem oi-slice; 8 nodes/thread.
// Same d-ascending f32 fma order + single f16 round as the proven in-gate build.
__global__ __launch_bounds__(256) void k_wall(const float* __restrict__ emb, int n0,
                                              const float* __restrict__ wt, int OI,
                                              _Float16* __restrict__ Wout) {
  int bx = blockIdx.x, by = blockIdx.y, tid = threadIdx.x;
  __shared__ float e_sh[64][16];
  {
    int node = tid >> 2, part = tid & 3;
    f32x4 v = *reinterpret_cast<const f32x4*>(emb + (n0 + bx * 64 + node) * 16 + part * 4);
    *reinterpret_cast<f32x4*>(&e_sh[node][part * 4]) = v;
  }
  __syncthreads();
  int oi0 = by * 2048 + tid * 8;
#pragma unroll
  for (int g = 0; g < 8; g++) {
    f32x4 a0[8], a1[8];
#pragma unroll
    for (int nn = 0; nn < 8; nn++) { a0[nn] = (f32x4){0,0,0,0}; a1[nn] = (f32x4){0,0,0,0}; }
#pragma unroll
    for (int d = 0; d < 16; d++) {
      const f32x4* p = reinterpret_cast<const f32x4*>(wt + d * OI + oi0);
      f32x4 v0 = p[0], v1 = p[1];
#pragma unroll
      for (int nn = 0; nn < 8; nn++) {
        float e = e_sh[g * 8 + nn][d];
        a0[nn] += e * v0;
        a1[nn] += e * v1;
      }
    }
#pragma unroll
    for (int nn = 0; nn < 8; nn++) {
      f16x8 pk;
#pragma unroll
      for (int q = 0; q < 4; q++) { pk[q] = (_Float16)a0[nn][q]; pk[4 + q] = (_Float16)a1[nn][q]; }
      *reinterpret_cast<f16x8*>(Wout + (size_t)(bx * 64 + g * 8 + nn) * OI + oi0) = pk;
    }
  }
}

// ---- 5b. gate (VALU, precomputed W chunk): z_r = sigmoid(x_g @ W_n + b_n) --
// Lane mapping: b0 = tid&15 (adjacent lanes 1 A-row apart -> 2-way, free),
// o0 = (tid>>4)*8 broadcast. A rows 136 (272 B, 16-aligned), W rows 140
// (8-row stride -> banks {0,16}, 2-way), W read as aligned f16x4 pairs.
__global__ __launch_bounds__(256) void k_gate(const _Float16* __restrict__ xg,   // [b][n][128]
                                              const float* __restrict__ emb,
                                              const _Float16* __restrict__ Wc,   // chunk [1024][128][128]
                                              const float* __restrict__ gbp,
                                              int n0,
                                              _Float16* __restrict__ zb,         // [n][b][64]
                                              _Float16* __restrict__ rb) {       // [n][b][64]
  int n = n0 + blockIdx.x, tid = threadIdx.x;
  __shared__ __attribute__((aligned(16))) _Float16 A[64][136];
  __shared__ __attribute__((aligned(16))) _Float16 W[128][140];
  __shared__ float bias_sh[128];
  // stage A
  {
    int b = tid >> 2, i0 = (tid & 3) * 32;
    const f16x8* s8 = reinterpret_cast<const f16x8*>(xg + (b * 4096 + n) * 128 + i0);
#pragma unroll
    for (int c = 0; c < 4; c++)
      *reinterpret_cast<f16x8*>(&A[b][i0 + c * 8]) = s8[c];
  }
  // stage W from global chunk (coalesced: 128 contiguous B per thread)
  {
    const _Float16* wrow = Wc + (size_t)blockIdx.x * 16384;
    int o = tid >> 1, ih = tid & 1;
#pragma unroll
    for (int k = 0; k < 8; k++) {
      f16x8 v = *reinterpret_cast<const f16x8*>(wrow + o * 128 + ih * 64 + k * 8);
      f16x4 lo = {v[0], v[1], v[2], v[3]}, hi = {v[4], v[5], v[6], v[7]};
      *reinterpret_cast<f16x4*>(&W[o][ih * 64 + k * 8]) = lo;
      *reinterpret_cast<f16x4*>(&W[o][ih * 64 + k * 8 + 4]) = hi;
    }
  }
  if (tid < 128) {
    float s = 0.f;
#pragma unroll
    for (int d = 0; d < 16; d++) s += emb[n * 16 + d] * gbp[d * 128 + tid];
    bias_sh[tid] = s;
  }
  __syncthreads();
  int b0 = tid & 15, o0 = (tid >> 4) * 8;
  float acc[4][8];
#pragma unroll
  for (int j = 0; j < 4; j++)
#pragma unroll
    for (int k = 0; k < 8; k++) acc[j][k] = bias_sh[o0 + k];
#pragma unroll
  for (int is = 0; is < 128; is += 8) {
    f16x8 av[4];
#pragma unroll
    for (int j = 0; j < 4; j++) av[j] = *reinterpret_cast<const f16x8*>(&A[b0 + j * 16][is]);
    f16x4 wlo[8], whi[8];
#pragma unroll
    for (int k = 0; k < 8; k++) {
      wlo[k] = *reinterpret_cast<const f16x4*>(&W[o0 + k][is]);
      whi[k] = *reinterpret_cast<const f16x4*>(&W[o0 + k][is + 4]);
    }
#pragma unroll
    for (int j = 0; j < 4; j++)
#pragma unroll
      for (int k = 0; k < 8; k++) {
#pragma unroll
        for (int q = 0; q < 4; q++) acc[j][k] += (float)av[j][q] * (float)wlo[k][q];
#pragma unroll
        for (int q = 0; q < 4; q++) acc[j][k] += (float)av[j][4 + q] * (float)whi[k][q];
      }
  }
#pragma unroll
  for (int j = 0; j < 4; j++) {
    int b = b0 + j * 16;
    f16x8 pk;
#pragma unroll
    for (int k = 0; k < 8; k++) pk[k] = (_Float16)(1.f / (1.f + __expf(-acc[j][k])));
    if (o0 < 64) *reinterpret_cast<f16x8*>(&zb[(n * 64 + b) * 64 + o0]) = pk;
    else         *reinterpret_cast<f16x8*>(&rb[(n * 64 + b) * 64 + (o0 - 64)]) = pk;
  }
}

// ------------- 6. xs_t[b][64+o][m] = f16(z[m][b][o] * state[b][m][o]) -------
__global__ __launch_bounds__(256) void k_cand(const _Float16* __restrict__ zb,
                                              const float* __restrict__ st,
                                              _Float16* __restrict__ xs_t) {
  int m0 = blockIdx.x * 64, b = blockIdx.y, tid = threadIdx.x;
  __shared__ __attribute__((aligned(16))) _Float16 T[64][66];
#pragma unroll
  for (int i = 0; i < 16; i++) {
    int li = i * 256 + tid, ml = li >> 6, o = li & 63;
    float z = (float)zb[((m0 + ml) * 64 + b) * 64 + o];
    float s = st[(b * 4096 + m0 + ml) * 64 + o];
    T[ml][o] = (_Float16)(z * s);
  }
  __syncthreads();
  int og = tid >> 3, mch = tid & 7;
#pragma unroll
  for (int cb = 0; cb < 2; cb++) {
    int o = cb * 32 + og;
    f16x8 tmp;
#pragma unroll
    for (int j = 0; j < 8; j++) tmp[j] = T[mch * 8 + j][o];
    *reinterpret_cast<f16x8*>(&xs_t[(b * 128 + 64 + o) * 4096 + m0 + mch * 8]) = tmp;
  }
}

// ---- 7. update (VALU, precomputed W chunk): hc=tanh(xg2 @ Wu_n + bu);
//      h = r*state + (1-r)*hc -> out. -----------------------------------------
__global__ __launch_bounds__(256) void k_upd(const _Float16* __restrict__ xg2,   // [b][n][128]
                                             const float* __restrict__ emb,
                                             const _Float16* __restrict__ Wc,    // chunk [2048][64][128]
                                             const float* __restrict__ ubp,
                                             int n0,
                                             const _Float16* __restrict__ rb,    // [n][b][64]
                                             const float* __restrict__ st,
                                             float* __restrict__ out) {
  int n = n0 + blockIdx.x, tid = threadIdx.x;
  __shared__ __attribute__((aligned(16))) _Float16 A[64][136];
  __shared__ __attribute__((aligned(16))) _Float16 W[64][140];
  __shared__ float bias_sh[64];
  // stage A
  {
    int b = tid >> 2, i0 = (tid & 3) * 32;
    const f16x8* s8 = reinterpret_cast<const f16x8*>(xg2 + (b * 4096 + n) * 128 + i0);
#pragma unroll
    for (int c = 0; c < 4; c++)
      *reinterpret_cast<f16x8*>(&A[b][i0 + c * 8]) = s8[c];
  }
  // stage W (quarter-row per thread, 64 contiguous B)
  {
    const _Float16* wrow = Wc + (size_t)blockIdx.x * 8192;
    int o = tid >> 2, q4 = tid & 3;
#pragma unroll
    for (int k = 0; k < 4; k++) {
      f16x8 v = *reinterpret_cast<const f16x8*>(wrow + o * 128 + q4 * 32 + k * 8);
      f16x4 lo = {v[0], v[1], v[2], v[3]}, hi = {v[4], v[5], v[6], v[7]};
      *reinterpret_cast<f16x4*>(&W[o][q4 * 32 + k * 8]) = lo;
      *reinterpret_cast<f16x4*>(&W[o][q4 * 32 + k * 8 + 4]) = hi;
    }
  }
  if (tid < 64) {
    float s = 0.f;
#pragma unroll
    for (int d = 0; d < 16; d++) s += emb[n * 16 + d] * ubp[d * 64 + tid];
    bias_sh[tid] = s;
  }
  __syncthreads();
  int b0 = tid & 15, o0 = (tid >> 4) * 4;
  float acc[4][4];
#pragma unroll
  for (int j = 0; j < 4; j++)
#pragma unroll
    for (int k = 0; k < 4; k++) acc[j][k] = bias_sh[o0 + k];
#pragma unroll
  for (int is = 0; is < 128; is += 8) {
    f16x8 av[4];
#pragma unroll
    for (int j = 0; j < 4; j++) av[j] = *reinterpret_cast<const f16x8*>(&A[b0 + j * 16][is]);
    f16x4 wlo[4], whi[4];
#pragma unroll
    for (int k = 0; k < 4; k++) {
      wlo[k] = *reinterpret_cast<const f16x4*>(&W[o0 + k][is]);
      whi[k] = *reinterpret_cast<const f16x4*>(&W[o0 + k][is + 4]);
    }
#pragma unroll
    for (int j = 0; j < 4; j++)
#pragma unroll
      for (int k = 0; k < 4; k++) {
#pragma unroll
        for (int q = 0; q < 4; q++) acc[j][k] += (float)av[j][q] * (float)wlo[k][q];
#pragma unroll
        for (int q = 0; q < 4; q++) acc[j][k] += (float)av[j][4 + q] * (float)whi[k][q];
      }
  }
#pragma unroll
  for (int j = 0; j < 4; j++) {
    int b = b0 + j * 16;
    const f32x4 s4 = *reinterpret_cast<const f32x4*>(&st[(b * 4096 + n) * 64 + o0]);
    f16x4 r4 = *reinterpret_cast<const f16x4*>(&rb[(n * 64 + b) * 64 + o0]);
    f32x4 o4;
#pragma unroll
    for (int k = 0; k < 4; k++) {
      float e2 = __expf(2.f * acc[j][k]);
      float hc = 1.f - 2.f / (e2 + 1.f);     // tanh
      float rr = (float)r4[k];
      o4[k] = rr * s4[k] + (1.f - rr) * hc;
    }
    *reinterpret_cast<f32x4*>(&out[(b * 4096 + n) * 64 + o0]) = o4;
  }
}

extern "C" void kernel_launch(void* const* d_in, const int* in_sizes, int n_in,
                              void* d_out, int out_size, void* d_ws, size_t ws_size,
                              hipStream_t stream) {
  const float* x   = (const float*)d_in[0];
  const float* st  = (const float*)d_in[1];
  const float* emb = (const float*)d_in[2];
  const float* gwp = (const float*)d_in[3];
  const float* gbp = (const float*)d_in[4];
  const float* uwp = (const float*)d_in[5];
  const float* ubp = (const float*)d_in[6];
  float* out = (float*)d_out;
  char* ws = (char*)d_ws;

  // slot A [0,33.55M): S for gemm1 -> W_all_g chunks -> S2 for gemm2
  _Float16* slotA = (_Float16*)(ws + 0);
  _Float16* xs_t  = (_Float16*)(ws + 33554432);   // 67 MB [b][c][m]
  _Float16* xg    = (_Float16*)(ws + 100663296);  // 67 MB (gemm1 out; gemm2 overwrites)
  _Float16* zb    = (_Float16*)(ws + 167772160);  // 33.5 MB [n][b][64]; -> W_all_u chunks after cand
  _Float16* rb    = (_Float16*)(ws + 201326592);  // 33.5 MB [n][b][64] (alive to upd)
  float* wtg = (float*)(ws + 234881024);          // 1 MB
  float* wtu = (float*)(ws + 235929600);          // 0.5 MB
  if (ws_size < 236453888ull) return;  // fail loudly rather than corrupt

  k_wpoolT<<<1536, 256, 0, stream>>>(gwp, uwp, wtg, wtu);
  k_supports<<<4096, 256, 0, stream>>>(emb, slotA);
  k_concat<<<dim3(64, 64), 256, 0, stream>>>(x, st, xs_t);
  k_gemm<<<dim3(32, 64), 256, 0, stream>>>(slotA, xs_t, xg);
  // gate in 4 chunks of 1024 nodes; W chunk (33.55 MB) reuses slot A (S dead)
  for (int c = 0; c < 4; c++) {
    k_wall<<<dim3(16, 8), 256, 0, stream>>>(emb, c * 1024, wtg, 16384, slotA);
    k_gate<<<1024, 256, 0, stream>>>(xg, emb, slotA, gbp, c * 1024, zb, rb);
  }
  k_cand<<<dim3(64, 64), 256, 0, stream>>>(zb, st, xs_t);
  k_supports<<<4096, 256, 0, stream>>>(emb, slotA);        // recompute S (cheap)
  k_gemm<<<dim3(32, 64), 256, 0, stream>>>(slotA, xs_t, xg);
  // update in 2 chunks of 2048 nodes; W chunk (33.55 MB) reuses zb slot (dead)
  for (int c = 0; c < 2; c++) {
    k_wall<<<dim3(32, 4), 256, 0, stream>>>(emb, c * 2048, wtu, 8192, zb);
    k_upd<<<2048, 256, 0, stream>>>(xg, emb, zb, ubp, c * 2048, rb, st, out);
  }
}

// Round 8
// 1290.042 us; speedup vs baseline: 1.9215x; 1.1009x over previous
//
#include <hip/hip_runtime.h>

typedef float f32x4 __attribute__((ext_vector_type(4)));
typedef _Float16 f16x8 __attribute__((ext_vector_type(8)));
typedef _Float16 f16x4 __attribute__((ext_vector_type(4)));

typedef __attribute__((address_space(1))) const unsigned char gbyte;
typedef __attribute__((address_space(3))) unsigned char sbyte;
__device__ __forceinline__ void gload_lds16(const void* gp, void* lp) {
  __builtin_amdgcn_global_load_lds((gbyte*)gp, (sbyte*)lp, 16, 0, 0);
}

// ---------------- 1. weight-pool transpose to [d][o][i], f32 ----------------
__global__ __launch_bounds__(256) void k_wpoolT(const float* __restrict__ gwp,
                                                const float* __restrict__ uwp,
                                                float* __restrict__ wtg,
                                                float* __restrict__ wtu) {
  int idx = blockIdx.x * 256 + threadIdx.x;
  if (idx < 16 * 128 * 128) {
    int d = idx >> 14, rem = idx & 16383, o = rem >> 7, i = rem & 127;
    wtg[idx] = gwp[(d << 14) + (i << 7) + o];          // gwp[d][i][o]
  } else {
    int j = idx - 16 * 128 * 128;
    if (j < 16 * 64 * 128) {
      int d = j >> 13, rem = j & 8191, o = rem >> 7, i = rem & 127;
      wtu[j] = uwp[(d << 13) + (i << 6) + o];          // uwp[d][i][o(64)]
    }
  }
}

// ---------------- 2. supports = softmax(relu(E E^T)) row-wise, f16 ----------
__global__ __launch_bounds__(256) void k_supports(const float* __restrict__ emb,
                                                  _Float16* __restrict__ S) {
  int n = blockIdx.x, tid = threadIdx.x;
  float en[16];
#pragma unroll
  for (int d = 0; d < 16; d++) en[d] = emb[n * 16 + d];
  float v[16];
  float sum = 0.f;
#pragma unroll
  for (int i = 0; i < 16; i++) {
    int m = i * 256 + tid;
    const float* em = emb + m * 16;
    float acc = 0.f;
#pragma unroll
    for (int d = 0; d < 16; d++) acc += en[d] * em[d];
    acc = fmaxf(acc, 0.f);
    float e = __expf(acc);
    v[i] = e;
    sum += e;
  }
#pragma unroll
  for (int off = 32; off > 0; off >>= 1) sum += __shfl_down(sum, off);
  __shared__ float red[4];
  if ((tid & 63) == 0) red[tid >> 6] = sum;
  __syncthreads();
  float inv = 1.f / (red[0] + red[1] + red[2] + red[3]);
#pragma unroll
  for (int i = 0; i < 16; i++) S[n * 4096 + i * 256 + tid] = (_Float16)(v[i] * inv);
}

// ------- 3. xs_t[b][c][m] = f16(concat(x,state))  (c-major for GEMM B) ------
__global__ __launch_bounds__(256) void k_concat(const float* __restrict__ x,
                                                const float* __restrict__ st,
                                                _Float16* __restrict__ xs_t) {
  int m0 = blockIdx.x * 64, b = blockIdx.y, tid = threadIdx.x;
  __shared__ __attribute__((aligned(16))) _Float16 T[64][130];
#pragma unroll
  for (int i = 0; i < 16; i++) {
    int li = i * 256 + tid;
    int ml = li >> 6, c = li & 63;
    int base = (b * 4096 + m0 + ml) * 64 + c;
    T[ml][c] = (_Float16)x[base];
    T[ml][64 + c] = (_Float16)st[base];
  }
  __syncthreads();
  int cg = tid >> 3, mch = tid & 7;
#pragma unroll
  for (int cb = 0; cb < 4; cb++) {
    int c = cb * 32 + cg;
    f16x8 tmp;
#pragma unroll
    for (int j = 0; j < 8; j++) tmp[j] = T[mch * 8 + j][c];
    *reinterpret_cast<f16x8*>(&xs_t[(b * 128 + c) * 4096 + m0 + mch * 8]) = tmp;
  }
}

// -------- 4. Y[b][n][c] = sum_m S[n][m] * xs_t[b][c][m]  (f16 MFMA) ---------
// T2 XOR-swizzle, rule-21 form: LDS dest linear (global_load_lds), global
// SOURCE column pre-swizzled, reads apply the same involution.
//   LDS slot (row, col) holds G[row][col ^ (row&7)*8]  (f16-elem units)
__global__ __launch_bounds__(256) void k_gemm(const _Float16* __restrict__ S,
                                              const _Float16* __restrict__ Xt,
                                              _Float16* __restrict__ Y) {
  int nt = blockIdx.x, b = blockIdx.y;
  int tid = threadIdx.x, lane = tid & 63, w = tid >> 6;
  int wr = w >> 1, wc = w & 1;
  __shared__ __attribute__((aligned(16))) _Float16 As[128 * 64];
  __shared__ __attribute__((aligned(16))) _Float16 Bs[128 * 64];
  const _Float16* Sb = S + nt * 128 * 4096;
  const _Float16* Xb = Xt + b * 128 * 4096;
  f32x4 acc[4][4];
#pragma unroll
  for (int m = 0; m < 4; m++)
#pragma unroll
    for (int n = 0; n < 4; n++) acc[m][n] = (f32x4){0.f, 0.f, 0.f, 0.f};

  int lrow = lane >> 3;                       // 0..7 (== row&7 of lane's row)
  int lcolsw = (((lane & 7) ^ lrow) * 8);     // pre-swizzled source column
  int lo = lane & 15, hi = lane >> 4;
  int xs = (lane & 7) * 8;                    // read-side XOR (elem units)
  for (int k0 = 0; k0 < 4096; k0 += 64) {
    __syncthreads();
#pragma unroll
    for (int i = 0; i < 4; i++) {
      int j = w * 4 + i;
      int row = j * 8 + lrow;
      gload_lds16(Sb + row * 4096 + k0 + lcolsw, &As[j * 512]);
      gload_lds16(Xb + row * 4096 + k0 + lcolsw, &Bs[j * 512]);
    }
    __syncthreads();
#pragma unroll
    for (int kk = 0; kk < 2; kk++) {
      int col = (kk * 32 + hi * 8) ^ xs;
      f16x8 af[4], bfr[4];
#pragma unroll
      for (int m = 0; m < 4; m++)
        af[m] = *reinterpret_cast<const f16x8*>(&As[(wr * 64 + m * 16 + lo) * 64 + col]);
#pragma unroll
      for (int n = 0; n < 4; n++)
        bfr[n] = *reinterpret_cast<const f16x8*>(&Bs[(wc * 64 + n * 16 + lo) * 64 + col]);
#pragma unroll
      for (int m = 0; m < 4; m++)
#pragma unroll
        for (int n = 0; n < 4; n++)
          acc[m][n] = __builtin_amdgcn_mfma_f32_16x16x32_f16(af[m], bfr[n], acc[m][n], 0, 0, 0);
    }
  }
  int r0 = (lane >> 4) * 4, cl = lane & 15;
#pragma unroll
  for (int m = 0; m < 4; m++)
#pragma unroll
    for (int r = 0; r < 4; r++) {
      int row = nt * 128 + wr * 64 + m * 16 + r0 + r;
#pragma unroll
      for (int n = 0; n < 4; n++) {
        int c = wc * 64 + n * 16 + cl;
        Y[(b * 4096 + row) * 128 + c] = (_Float16)acc[m][n][r];
      }
    }
}

// ---- 5a. k_wall: W_all[nn][o*i] = f16( sum_d E[n0+nn][d] * wt[d][o*i] ) ----
__global__ __launch_bounds__(256) void k_wall(const float* __restrict__ emb, int n0,
                                              const float* __restrict__ wt, int OI,
                                              _Float16* __restrict__ Wout) {
  int bx = blockIdx.x, by = blockIdx.y, tid = threadIdx.x;
  __shared__ float e_sh[64][16];
  {
    int node = tid >> 2, part = tid & 3;
    f32x4 v = *reinterpret_cast<const f32x4*>(emb + (n0 + bx * 64 + node) * 16 + part * 4);
    *reinterpret_cast<f32x4*>(&e_sh[node][part * 4]) = v;
  }
  __syncthreads();
  int oi0 = by * 2048 + tid * 8;
#pragma unroll
  for (int g = 0; g < 8; g++) {
    f32x4 a0[8], a1[8];
#pragma unroll
    for (int nn = 0; nn < 8; nn++) { a0[nn] = (f32x4){0,0,0,0}; a1[nn] = (f32x4){0,0,0,0}; }
#pragma unroll
    for (int d = 0; d < 16; d++) {
      const f32x4* p = reinterpret_cast<const f32x4*>(wt + d * OI + oi0);
      f32x4 v0 = p[0], v1 = p[1];
#pragma unroll
      for (int nn = 0; nn < 8; nn++) {
        float e = e_sh[g * 8 + nn][d];
        a0[nn] += e * v0;
        a1[nn] += e * v1;
      }
    }
#pragma unroll
    for (int nn = 0; nn < 8; nn++) {
      f16x8 pk;
#pragma unroll
      for (int q = 0; q < 4; q++) { pk[q] = (_Float16)a0[nn][q]; pk[4 + q] = (_Float16)a1[nn][q]; }
      *reinterpret_cast<f16x8*>(Wout + (size_t)(bx * 64 + g * 8 + nn) * OI + oi0) = pk;
    }
  }
}

// ---- 5b. gate (VALU, precomputed W chunk): z_r = sigmoid(x_g @ W_n + b_n) --
__global__ __launch_bounds__(256) void k_gate(const _Float16* __restrict__ xg,   // [b][n][128]
                                              const float* __restrict__ emb,
                                              const _Float16* __restrict__ Wc,   // chunk [1024][128][128]
                                              const float* __restrict__ gbp,
                                              int n0,
                                              _Float16* __restrict__ zb,         // [n][b][64]
                                              _Float16* __restrict__ rb) {       // [n][b][64]
  int n = n0 + blockIdx.x, tid = threadIdx.x;
  __shared__ __attribute__((aligned(16))) _Float16 A[64][136];
  __shared__ __attribute__((aligned(16))) _Float16 W[128][140];
  __shared__ float bias_sh[128];
  // stage A
  {
    int b = tid >> 2, i0 = (tid & 3) * 32;
    const f16x8* s8 = reinterpret_cast<const f16x8*>(xg + (b * 4096 + n) * 128 + i0);
#pragma unroll
    for (int c = 0; c < 4; c++)
      *reinterpret_cast<f16x8*>(&A[b][i0 + c * 8]) = s8[c];
  }
  // stage W from global chunk (coalesced: 128 contiguous B per thread)
  {
    const _Float16* wrow = Wc + (size_t)blockIdx.x * 16384;
    int o = tid >> 1, ih = tid & 1;
#pragma unroll
    for (int k = 0; k < 8; k++) {
      f16x8 v = *reinterpret_cast<const f16x8*>(wrow + o * 128 + ih * 64 + k * 8);
      f16x4 lo = {v[0], v[1], v[2], v[3]}, hi = {v[4], v[5], v[6], v[7]};
      *reinterpret_cast<f16x4*>(&W[o][ih * 64 + k * 8]) = lo;
      *reinterpret_cast<f16x4*>(&W[o][ih * 64 + k * 8 + 4]) = hi;
    }
  }
  if (tid < 128) {
    float s = 0.f;
#pragma unroll
    for (int d = 0; d < 16; d++) s += emb[n * 16 + d] * gbp[d * 128 + tid];
    bias_sh[tid] = s;
  }
  __syncthreads();
  int b0 = tid & 15, o0 = (tid >> 4) * 8;
  float acc[4][8];
#pragma unroll
  for (int j = 0; j < 4; j++)
#pragma unroll
    for (int k = 0; k < 8; k++) acc[j][k] = bias_sh[o0 + k];
#pragma unroll
  for (int is = 0; is < 128; is += 8) {
    f16x8 av[4];
#pragma unroll
    for (int j = 0; j < 4; j++) av[j] = *reinterpret_cast<const f16x8*>(&A[b0 + j * 16][is]);
    f16x4 wlo[8], whi[8];
#pragma unroll
    for (int k = 0; k < 8; k++) {
      wlo[k] = *reinterpret_cast<const f16x4*>(&W[o0 + k][is]);
      whi[k] = *reinterpret_cast<const f16x4*>(&W[o0 + k][is + 4]);
    }
#pragma unroll
    for (int j = 0; j < 4; j++)
#pragma unroll
      for (int k = 0; k < 8; k++) {
#pragma unroll
        for (int q = 0; q < 4; q++) acc[j][k] += (float)av[j][q] * (float)wlo[k][q];
#pragma unroll
        for (int q = 0; q < 4; q++) acc[j][k] += (float)av[j][4 + q] * (float)whi[k][q];
      }
  }
#pragma unroll
  for (int j = 0; j < 4; j++) {
    int b = b0 + j * 16;
    f16x8 pk;
#pragma unroll
    for (int k = 0; k < 8; k++) pk[k] = (_Float16)(1.f / (1.f + __expf(-acc[j][k])));
    if (o0 < 64) *reinterpret_cast<f16x8*>(&zb[(n * 64 + b) * 64 + o0]) = pk;
    else         *reinterpret_cast<f16x8*>(&rb[(n * 64 + b) * 64 + (o0 - 64)]) = pk;
  }
}

// ------------- 6. xs_t[b][64+o][m] = f16(z[m][b][o] * state[b][m][o]) -------
__global__ __launch_bounds__(256) void k_cand(const _Float16* __restrict__ zb,
                                              const float* __restrict__ st,
                                              _Float16* __restrict__ xs_t) {
  int m0 = blockIdx.x * 64, b = blockIdx.y, tid = threadIdx.x;
  __shared__ __attribute__((aligned(16))) _Float16 T[64][66];
#pragma unroll
  for (int i = 0; i < 16; i++) {
    int li = i * 256 + tid, ml = li >> 6, o = li & 63;
    float z = (float)zb[((m0 + ml) * 64 + b) * 64 + o];
    float s = st[(b * 4096 + m0 + ml) * 64 + o];
    T[ml][o] = (_Float16)(z * s);
  }
  __syncthreads();
  int og = tid >> 3, mch = tid & 7;
#pragma unroll
  for (int cb = 0; cb < 2; cb++) {
    int o = cb * 32 + og;
    f16x8 tmp;
#pragma unroll
    for (int j = 0; j < 8; j++) tmp[j] = T[mch * 8 + j][o];
    *reinterpret_cast<f16x8*>(&xs_t[(b * 128 + 64 + o) * 4096 + m0 + mch * 8]) = tmp;
  }
}

// ---- 7. update (VALU, precomputed W chunk): hc=tanh(xg2 @ Wu_n + bu);
//      h = r*state + (1-r)*hc -> out. -----------------------------------------
__global__ __launch_bounds__(256) void k_upd(const _Float16* __restrict__ xg2,   // [b][n][128]
                                             const float* __restrict__ emb,
                                             const _Float16* __restrict__ Wc,    // chunk [2048][64][128]
                                             const float* __restrict__ ubp,
                                             int n0,
                                             const _Float16* __restrict__ rb,    // [n][b][64]
                                             const float* __restrict__ st,
                                             float* __restrict__ out) {
  int n = n0 + blockIdx.x, tid = threadIdx.x;
  __shared__ __attribute__((aligned(16))) _Float16 A[64][136];
  __shared__ __attribute__((aligned(16))) _Float16 W[64][140];
  __shared__ float bias_sh[64];
  // stage A
  {
    int b = tid >> 2, i0 = (tid & 3) * 32;
    const f16x8* s8 = reinterpret_cast<const f16x8*>(xg2 + (b * 4096 + n) * 128 + i0);
#pragma unroll
    for (int c = 0; c < 4; c++)
      *reinterpret_cast<f16x8*>(&A[b][i0 + c * 8]) = s8[c];
  }
  // stage W (quarter-row per thread, 64 contiguous B)
  {
    const _Float16* wrow = Wc + (size_t)blockIdx.x * 8192;
    int o = tid >> 2, q4 = tid & 3;
#pragma unroll
    for (int k = 0; k < 4; k++) {
      f16x8 v = *reinterpret_cast<const f16x8*>(wrow + o * 128 + q4 * 32 + k * 8);
      f16x4 lo = {v[0], v[1], v[2], v[3]}, hi = {v[4], v[5], v[6], v[7]};
      *reinterpret_cast<f16x4*>(&W[o][q4 * 32 + k * 8]) = lo;
      *reinterpret_cast<f16x4*>(&W[o][q4 * 32 + k * 8 + 4]) = hi;
    }
  }
  if (tid < 64) {
    float s = 0.f;
#pragma unroll
    for (int d = 0; d < 16; d++) s += emb[n * 16 + d] * ubp[d * 64 + tid];
    bias_sh[tid] = s;
  }
  __syncthreads();
  int b0 = tid & 15, o0 = (tid >> 4) * 4;
  float acc[4][4];
#pragma unroll
  for (int j = 0; j < 4; j++)
#pragma unroll
    for (int k = 0; k < 4; k++) acc[j][k] = bias_sh[o0 + k];
#pragma unroll
  for (int is = 0; is < 128; is += 8) {
    f16x8 av[4];
#pragma unroll
    for (int j = 0; j < 4; j++) av[j] = *reinterpret_cast<const f16x8*>(&A[b0 + j * 16][is]);
    f16x4 wlo[4], whi[4];
#pragma unroll
    for (int k = 0; k < 4; k++) {
      wlo[k] = *reinterpret_cast<const f16x4*>(&W[o0 + k][is]);
      whi[k] = *reinterpret_cast<const f16x4*>(&W[o0 + k][is + 4]);
    }
#pragma unroll
    for (int j = 0; j < 4; j++)
#pragma unroll
      for (int k = 0; k < 4; k++) {
#pragma unroll
        for (int q = 0; q < 4; q++) acc[j][k] += (float)av[j][q] * (float)wlo[k][q];
#pragma unroll
        for (int q = 0; q < 4; q++) acc[j][k] += (float)av[j][4 + q] * (float)whi[k][q];
      }
  }
#pragma unroll
  for (int j = 0; j < 4; j++) {
    int b = b0 + j * 16;
    const f32x4 s4 = *reinterpret_cast<const f32x4*>(&st[(b * 4096 + n) * 64 + o0]);
    f16x4 r4 = *reinterpret_cast<const f16x4*>(&rb[(n * 64 + b) * 64 + o0]);
    f32x4 o4;
#pragma unroll
    for (int k = 0; k < 4; k++) {
      float e2 = __expf(2.f * acc[j][k]);
      float hc = 1.f - 2.f / (e2 + 1.f);     // tanh
      float rr = (float)r4[k];
      o4[k] = rr * s4[k] + (1.f - rr) * hc;
    }
    *reinterpret_cast<f32x4*>(&out[(b * 4096 + n) * 64 + o0]) = o4;
  }
}

extern "C" void kernel_launch(void* const* d_in, const int* in_sizes, int n_in,
                              void* d_out, int out_size, void* d_ws, size_t ws_size,
                              hipStream_t stream) {
  const float* x   = (const float*)d_in[0];
  const float* st  = (const float*)d_in[1];
  const float* emb = (const float*)d_in[2];
  const float* gwp = (const float*)d_in[3];
  const float* gbp = (const float*)d_in[4];
  const float* uwp = (const float*)d_in[5];
  const float* ubp = (const float*)d_in[6];
  float* out = (float*)d_out;
  char* ws = (char*)d_ws;

  // slot A [0,33.55M): S for gemm1 -> W_all_g chunks -> S2 for gemm2
  _Float16* slotA = (_Float16*)(ws + 0);
  _Float16* xs_t  = (_Float16*)(ws + 33554432);   // 67 MB [b][c][m]
  _Float16* xg    = (_Float16*)(ws + 100663296);  // 67 MB (gemm1 out; gemm2 overwrites)
  _Float16* zb    = (_Float16*)(ws + 167772160);  // 33.5 MB [n][b][64]; -> W_all_u chunks after cand
  _Float16* rb    = (_Float16*)(ws + 201326592);  // 33.5 MB [n][b][64] (alive to upd)
  float* wtg = (float*)(ws + 234881024);          // 1 MB
  float* wtu = (float*)(ws + 235929600);          // 0.5 MB
  if (ws_size < 236453888ull) return;  // fail loudly rather than corrupt

  k_wpoolT<<<1536, 256, 0, stream>>>(gwp, uwp, wtg, wtu);
  k_supports<<<4096, 256, 0, stream>>>(emb, slotA);
  k_concat<<<dim3(64, 64), 256, 0, stream>>>(x, st, xs_t);
  k_gemm<<<dim3(32, 64), 256, 0, stream>>>(slotA, xs_t, xg);
  // gate in 4 chunks of 1024 nodes; W chunk (33.55 MB) reuses slot A (S dead)
  for (int c = 0; c < 4; c++) {
    k_wall<<<dim3(16, 8), 256, 0, stream>>>(emb, c * 1024, wtg, 16384, slotA);
    k_gate<<<1024, 256, 0, stream>>>(xg, emb, slotA, gbp, c * 1024, zb, rb);
  }
  k_cand<<<dim3(64, 64), 256, 0, stream>>>(zb, st, xs_t);
  k_supports<<<4096, 256, 0, stream>>>(emb, slotA);        // recompute S (cheap)
  k_gemm<<<dim3(32, 64), 256, 0, stream>>>(slotA, xs_t, xg);
  // update in 2 chunks of 2048 nodes; W chunk (33.55 MB) reuses zb slot (dead)
  for (int c = 0; c < 2; c++) {
    k_wall<<<dim3(32, 4), 256, 0, stream>>>(emb, c * 2048, wtu, 8192, zb);
    k_upd<<<2048, 256, 0, stream>>>(xg, emb, zb, ubp, c * 2048, rb, st, out);
  }
}

// Round 9
// 1218.239 us; speedup vs baseline: 2.0347x; 1.0589x over previous
//
#include <hip/hip_runtime.h>

typedef float f32x4 __attribute__((ext_vector_type(4)));
typedef _Float16 f16x8 __attribute__((ext_vector_type(8)));
typedef _Float16 f16x4 __attribute__((ext_vector_type(4)));
typedef _Float16 f16x2 __attribute__((ext_vector_type(2)));

typedef __attribute__((address_space(1))) const unsigned char gbyte;
typedef __attribute__((address_space(3))) unsigned char sbyte;
__device__ __forceinline__ void gload_lds16(const void* gp, void* lp) {
  __builtin_amdgcn_global_load_lds((gbyte*)gp, (sbyte*)lp, 16, 0, 0);
}

// packed f16 dot2 with f32 accumulate (v_dot2_f32_f16); fallback = R8 numerics
#if __has_builtin(__builtin_amdgcn_fdot2)
__device__ __forceinline__ float fdot2(f16x2 a, f16x2 b, float c) {
  return __builtin_amdgcn_fdot2(a, b, c, false);
}
#else
__device__ __forceinline__ float fdot2(f16x2 a, f16x2 b, float c) {
  return c + (float)a[0] * (float)b[0] + (float)a[1] * (float)b[1];
}
#endif

// ---------------- 1. weight-pool transpose to [d][o][i], f32 ----------------
__global__ __launch_bounds__(256) void k_wpoolT(const float* __restrict__ gwp,
                                                const float* __restrict__ uwp,
                                                float* __restrict__ wtg,
                                                float* __restrict__ wtu) {
  int idx = blockIdx.x * 256 + threadIdx.x;
  if (idx < 16 * 128 * 128) {
    int d = idx >> 14, rem = idx & 16383, o = rem >> 7, i = rem & 127;
    wtg[idx] = gwp[(d << 14) + (i << 7) + o];          // gwp[d][i][o]
  } else {
    int j = idx - 16 * 128 * 128;
    if (j < 16 * 64 * 128) {
      int d = j >> 13, rem = j & 8191, o = rem >> 7, i = rem & 127;
      wtu[j] = uwp[(d << 13) + (i << 6) + o];          // uwp[d][i][o(64)]
    }
  }
}

// ---------------- 2. supports = softmax(relu(E E^T)) row-wise, f16 ----------
__global__ __launch_bounds__(256) void k_supports(const float* __restrict__ emb,
                                                  _Float16* __restrict__ S) {
  int n = blockIdx.x, tid = threadIdx.x;
  float en[16];
#pragma unroll
  for (int d = 0; d < 16; d++) en[d] = emb[n * 16 + d];
  float v[16];
  float sum = 0.f;
#pragma unroll
  for (int i = 0; i < 16; i++) {
    int m = i * 256 + tid;
    const float* em = emb + m * 16;
    float acc = 0.f;
#pragma unroll
    for (int d = 0; d < 16; d++) acc += en[d] * em[d];
    acc = fmaxf(acc, 0.f);
    float e = __expf(acc);
    v[i] = e;
    sum += e;
  }
#pragma unroll
  for (int off = 32; off > 0; off >>= 1) sum += __shfl_down(sum, off);
  __shared__ float red[4];
  if ((tid & 63) == 0) red[tid >> 6] = sum;
  __syncthreads();
  float inv = 1.f / (red[0] + red[1] + red[2] + red[3]);
#pragma unroll
  for (int i = 0; i < 16; i++) S[n * 4096 + i * 256 + tid] = (_Float16)(v[i] * inv);
}

// ------- 3. xs_t[b][c][m] = f16(concat(x,state))  (c-major for GEMM B) ------
__global__ __launch_bounds__(256) void k_concat(const float* __restrict__ x,
                                                const float* __restrict__ st,
                                                _Float16* __restrict__ xs_t) {
  int m0 = blockIdx.x * 64, b = blockIdx.y, tid = threadIdx.x;
  __shared__ __attribute__((aligned(16))) _Float16 T[64][130];
#pragma unroll
  for (int i = 0; i < 16; i++) {
    int li = i * 256 + tid;
    int ml = li >> 6, c = li & 63;
    int base = (b * 4096 + m0 + ml) * 64 + c;
    T[ml][c] = (_Float16)x[base];
    T[ml][64 + c] = (_Float16)st[base];
  }
  __syncthreads();
  int cg = tid >> 3, mch = tid & 7;
#pragma unroll
  for (int cb = 0; cb < 4; cb++) {
    int c = cb * 32 + cg;
    f16x8 tmp;
#pragma unroll
    for (int j = 0; j < 8; j++) tmp[j] = T[mch * 8 + j][c];
    *reinterpret_cast<f16x8*>(&xs_t[(b * 128 + c) * 4096 + m0 + mch * 8]) = tmp;
  }
}

// -------- 4. Y[b][n][c] = sum_m S[n][m] * xs_t[b][c][m]  (f16 MFMA) ---------
// T2 XOR-swizzle, rule-21 form (proven R8): LDS dest linear, global SOURCE
// column pre-swizzled, reads apply the same involution.
__global__ __launch_bounds__(256) void k_gemm(const _Float16* __restrict__ S,
                                              const _Float16* __restrict__ Xt,
                                              _Float16* __restrict__ Y) {
  int nt = blockIdx.x, b = blockIdx.y;
  int tid = threadIdx.x, lane = tid & 63, w = tid >> 6;
  int wr = w >> 1, wc = w & 1;
  __shared__ __attribute__((aligned(16))) _Float16 As[128 * 64];
  __shared__ __attribute__((aligned(16))) _Float16 Bs[128 * 64];
  const _Float16* Sb = S + nt * 128 * 4096;
  const _Float16* Xb = Xt + b * 128 * 4096;
  f32x4 acc[4][4];
#pragma unroll
  for (int m = 0; m < 4; m++)
#pragma unroll
    for (int n = 0; n < 4; n++) acc[m][n] = (f32x4){0.f, 0.f, 0.f, 0.f};

  int lrow = lane >> 3;                       // 0..7 (== row&7 of lane's row)
  int lcolsw = (((lane & 7) ^ lrow) * 8);     // pre-swizzled source column
  int lo = lane & 15, hi = lane >> 4;
  int xs = (lane & 7) * 8;                    // read-side XOR (elem units)
  for (int k0 = 0; k0 < 4096; k0 += 64) {
    __syncthreads();
#pragma unroll
    for (int i = 0; i < 4; i++) {
      int j = w * 4 + i;
      int row = j * 8 + lrow;
      gload_lds16(Sb + row * 4096 + k0 + lcolsw, &As[j * 512]);
      gload_lds16(Xb + row * 4096 + k0 + lcolsw, &Bs[j * 512]);
    }
    __syncthreads();
#pragma unroll
    for (int kk = 0; kk < 2; kk++) {
      int col = (kk * 32 + hi * 8) ^ xs;
      f16x8 af[4], bfr[4];
#pragma unroll
      for (int m = 0; m < 4; m++)
        af[m] = *reinterpret_cast<const f16x8*>(&As[(wr * 64 + m * 16 + lo) * 64 + col]);
#pragma unroll
      for (int n = 0; n < 4; n++)
        bfr[n] = *reinterpret_cast<const f16x8*>(&Bs[(wc * 64 + n * 16 + lo) * 64 + col]);
#pragma unroll
      for (int m = 0; m < 4; m++)
#pragma unroll
        for (int n = 0; n < 4; n++)
          acc[m][n] = __builtin_amdgcn_mfma_f32_16x16x32_f16(af[m], bfr[n], acc[m][n], 0, 0, 0);
    }
  }
  int r0 = (lane >> 4) * 4, cl = lane & 15;
#pragma unroll
  for (int m = 0; m < 4; m++)
#pragma unroll
    for (int r = 0; r < 4; r++) {
      int row = nt * 128 + wr * 64 + m * 16 + r0 + r;
#pragma unroll
      for (int n = 0; n < 4; n++) {
        int c = wc * 64 + n * 16 + cl;
        Y[(b * 4096 + row) * 128 + c] = (_Float16)acc[m][n][r];
      }
    }
}

// ---- 5a. k_wall: W_all[nn][o*i] = f16( sum_d E[n0+nn][d] * wt[d][o*i] ) ----
__global__ __launch_bounds__(256) void k_wall(const float* __restrict__ emb, int n0,
                                              const float* __restrict__ wt, int OI,
                                              _Float16* __restrict__ Wout) {
  int bx = blockIdx.x, by = blockIdx.y, tid = threadIdx.x;
  __shared__ float e_sh[64][16];
  {
    int node = tid >> 2, part = tid & 3;
    f32x4 v = *reinterpret_cast<const f32x4*>(emb + (n0 + bx * 64 + node) * 16 + part * 4);
    *reinterpret_cast<f32x4*>(&e_sh[node][part * 4]) = v;
  }
  __syncthreads();
  int oi0 = by * 2048 + tid * 8;
#pragma unroll
  for (int g = 0; g < 8; g++) {
    f32x4 a0[8], a1[8];
#pragma unroll
    for (int nn = 0; nn < 8; nn++) { a0[nn] = (f32x4){0,0,0,0}; a1[nn] = (f32x4){0,0,0,0}; }
#pragma unroll
    for (int d = 0; d < 16; d++) {
      const f32x4* p = reinterpret_cast<const f32x4*>(wt + d * OI + oi0);
      f32x4 v0 = p[0], v1 = p[1];
#pragma unroll
      for (int nn = 0; nn < 8; nn++) {
        float e = e_sh[g * 8 + nn][d];
        a0[nn] += e * v0;
        a1[nn] += e * v1;
      }
    }
#pragma unroll
    for (int nn = 0; nn < 8; nn++) {
      f16x8 pk;
#pragma unroll
      for (int q = 0; q < 4; q++) { pk[q] = (_Float16)a0[nn][q]; pk[4 + q] = (_Float16)a1[nn][q]; }
      *reinterpret_cast<f16x8*>(Wout + (size_t)(bx * 64 + g * 8 + nn) * OI + oi0) = pk;
    }
  }
}

// ---- 5b. gate (dot2 VALU, precomputed W chunk): sigmoid(x_g @ W_n + b_n) ---
__global__ __launch_bounds__(256) void k_gate(const _Float16* __restrict__ xg,   // [b][n][128]
                                              const float* __restrict__ emb,
                                              const _Float16* __restrict__ Wc,   // chunk [1024][128][128]
                                              const float* __restrict__ gbp,
                                              int n0,
                                              _Float16* __restrict__ zb,         // [n][b][64]
                                              _Float16* __restrict__ rb) {       // [n][b][64]
  int n = n0 + blockIdx.x, tid = threadIdx.x;
  __shared__ __attribute__((aligned(16))) _Float16 A[64][136];
  __shared__ __attribute__((aligned(16))) _Float16 W[128][140];
  __shared__ float bias_sh[128];
  // stage A
  {
    int b = tid >> 2, i0 = (tid & 3) * 32;
    const f16x8* s8 = reinterpret_cast<const f16x8*>(xg + (b * 4096 + n) * 128 + i0);
#pragma unroll
    for (int c = 0; c < 4; c++)
      *reinterpret_cast<f16x8*>(&A[b][i0 + c * 8]) = s8[c];
  }
  // stage W from global chunk (coalesced: 128 contiguous B per thread)
  {
    const _Float16* wrow = Wc + (size_t)blockIdx.x * 16384;
    int o = tid >> 1, ih = tid & 1;
#pragma unroll
    for (int k = 0; k < 8; k++) {
      f16x8 v = *reinterpret_cast<const f16x8*>(wrow + o * 128 + ih * 64 + k * 8);
      f16x4 lo = {v[0], v[1], v[2], v[3]}, hi = {v[4], v[5], v[6], v[7]};
      *reinterpret_cast<f16x4*>(&W[o][ih * 64 + k * 8]) = lo;
      *reinterpret_cast<f16x4*>(&W[o][ih * 64 + k * 8 + 4]) = hi;
    }
  }
  if (tid < 128) {
    float s = 0.f;
#pragma unroll
    for (int d = 0; d < 16; d++) s += emb[n * 16 + d] * gbp[d * 128 + tid];
    bias_sh[tid] = s;
  }
  __syncthreads();
  int b0 = tid & 15, o0 = (tid >> 4) * 8;
  float acc[4][8];
#pragma unroll
  for (int j = 0; j < 4; j++)
#pragma unroll
    for (int k = 0; k < 8; k++) acc[j][k] = bias_sh[o0 + k];
#pragma unroll
  for (int is = 0; is < 128; is += 8) {
    f16x8 av[4];
#pragma unroll
    for (int j = 0; j < 4; j++) av[j] = *reinterpret_cast<const f16x8*>(&A[b0 + j * 16][is]);
    f16x2 ap[4][4];
#pragma unroll
    for (int j = 0; j < 4; j++) {
      ap[j][0] = (f16x2){av[j][0], av[j][1]};
      ap[j][1] = (f16x2){av[j][2], av[j][3]};
      ap[j][2] = (f16x2){av[j][4], av[j][5]};
      ap[j][3] = (f16x2){av[j][6], av[j][7]};
    }
#pragma unroll
    for (int k = 0; k < 8; k++) {
      f16x4 wlo = *reinterpret_cast<const f16x4*>(&W[o0 + k][is]);
      f16x4 whi = *reinterpret_cast<const f16x4*>(&W[o0 + k][is + 4]);
      f16x2 w0 = (f16x2){wlo[0], wlo[1]}, w1 = (f16x2){wlo[2], wlo[3]};
      f16x2 w2 = (f16x2){whi[0], whi[1]}, w3 = (f16x2){whi[2], whi[3]};
#pragma unroll
      for (int j = 0; j < 4; j++) {
        float a = acc[j][k];
        a = fdot2(ap[j][0], w0, a);
        a = fdot2(ap[j][1], w1, a);
        a = fdot2(ap[j][2], w2, a);
        a = fdot2(ap[j][3], w3, a);
        acc[j][k] = a;
      }
    }
  }
#pragma unroll
  for (int j = 0; j < 4; j++) {
    int b = b0 + j * 16;
    f16x8 pk;
#pragma unroll
    for (int k = 0; k < 8; k++) pk[k] = (_Float16)(1.f / (1.f + __expf(-acc[j][k])));
    if (o0 < 64) *reinterpret_cast<f16x8*>(&zb[(n * 64 + b) * 64 + o0]) = pk;
    else         *reinterpret_cast<f16x8*>(&rb[(n * 64 + b) * 64 + (o0 - 64)]) = pk;
  }
}

// ------------- 6. xs_t[b][64+o][m] = f16(z[m][b][o] * state[b][m][o]) -------
__global__ __launch_bounds__(256) void k_cand(const _Float16* __restrict__ zb,
                                              const float* __restrict__ st,
                                              _Float16* __restrict__ xs_t) {
  int m0 = blockIdx.x * 64, b = blockIdx.y, tid = threadIdx.x;
  __shared__ __attribute__((aligned(16))) _Float16 T[64][66];
#pragma unroll
  for (int i = 0; i < 16; i++) {
    int li = i * 256 + tid, ml = li >> 6, o = li & 63;
    float z = (float)zb[((m0 + ml) * 64 + b) * 64 + o];
    float s = st[(b * 4096 + m0 + ml) * 64 + o];
    T[ml][o] = (_Float16)(z * s);
  }
  __syncthreads();
  int og = tid >> 3, mch = tid & 7;
#pragma unroll
  for (int cb = 0; cb < 2; cb++) {
    int o = cb * 32 + og;
    f16x8 tmp;
#pragma unroll
    for (int j = 0; j < 8; j++) tmp[j] = T[mch * 8 + j][o];
    *reinterpret_cast<f16x8*>(&xs_t[(b * 128 + 64 + o) * 4096 + m0 + mch * 8]) = tmp;
  }
}

// ---- 7. update (dot2 VALU, precomputed W chunk): hc=tanh(xg2 @ Wu_n + bu);
//      h = r*state + (1-r)*hc -> out. -----------------------------------------
__global__ __launch_bounds__(256) void k_upd(const _Float16* __restrict__ xg2,   // [b][n][128]
                                             const float* __restrict__ emb,
                                             const _Float16* __restrict__ Wc,    // chunk [2048][64][128]
                                             const float* __restrict__ ubp,
                                             int n0,
                                             const _Float16* __restrict__ rb,    // [n][b][64]
                                             const float* __restrict__ st,
                                             float* __restrict__ out) {
  int n = n0 + blockIdx.x, tid = threadIdx.x;
  __shared__ __attribute__((aligned(16))) _Float16 A[64][136];
  __shared__ __attribute__((aligned(16))) _Float16 W[64][140];
  __shared__ float bias_sh[64];
  // stage A
  {
    int b = tid >> 2, i0 = (tid & 3) * 32;
    const f16x8* s8 = reinterpret_cast<const f16x8*>(xg2 + (b * 4096 + n) * 128 + i0);
#pragma unroll
    for (int c = 0; c < 4; c++)
      *reinterpret_cast<f16x8*>(&A[b][i0 + c * 8]) = s8[c];
  }
  // stage W (quarter-row per thread, 64 contiguous B)
  {
    const _Float16* wrow = Wc + (size_t)blockIdx.x * 8192;
    int o = tid >> 2, q4 = tid & 3;
#pragma unroll
    for (int k = 0; k < 4; k++) {
      f16x8 v = *reinterpret_cast<const f16x8*>(wrow + o * 128 + q4 * 32 + k * 8);
      f16x4 lo = {v[0], v[1], v[2], v[3]}, hi = {v[4], v[5], v[6], v[7]};
      *reinterpret_cast<f16x4*>(&W[o][q4 * 32 + k * 8]) = lo;
      *reinterpret_cast<f16x4*>(&W[o][q4 * 32 + k * 8 + 4]) = hi;
    }
  }
  if (tid < 64) {
    float s = 0.f;
#pragma unroll
    for (int d = 0; d < 16; d++) s += emb[n * 16 + d] * ubp[d * 64 + tid];
    bias_sh[tid] = s;
  }
  __syncthreads();
  int b0 = tid & 15, o0 = (tid >> 4) * 4;
  float acc[4][4];
#pragma unroll
  for (int j = 0; j < 4; j++)
#pragma unroll
    for (int k = 0; k < 4; k++) acc[j][k] = bias_sh[o0 + k];
#pragma unroll
  for (int is = 0; is < 128; is += 8) {
    f16x8 av[4];
#pragma unroll
    for (int j = 0; j < 4; j++) av[j] = *reinterpret_cast<const f16x8*>(&A[b0 + j * 16][is]);
    f16x2 ap[4][4];
#pragma unroll
    for (int j = 0; j < 4; j++) {
      ap[j][0] = (f16x2){av[j][0], av[j][1]};
      ap[j][1] = (f16x2){av[j][2], av[j][3]};
      ap[j][2] = (f16x2){av[j][4], av[j][5]};
      ap[j][3] = (f16x2){av[j][6], av[j][7]};
    }
#pragma unroll
    for (int k = 0; k < 4; k++) {
      f16x4 wlo = *reinterpret_cast<const f16x4*>(&W[o0 + k][is]);
      f16x4 whi = *reinterpret_cast<const f16x4*>(&W[o0 + k][is + 4]);
      f16x2 w0 = (f16x2){wlo[0], wlo[1]}, w1 = (f16x2){wlo[2], wlo[3]};
      f16x2 w2 = (f16x2){whi[0], whi[1]}, w3 = (f16x2){whi[2], whi[3]};
#pragma unroll
      for (int j = 0; j < 4; j++) {
        float a = acc[j][k];
        a = fdot2(ap[j][0], w0, a);
        a = fdot2(ap[j][1], w1, a);
        a = fdot2(ap[j][2], w2, a);
        a = fdot2(ap[j][3], w3, a);
        acc[j][k] = a;
      }
    }
  }
#pragma unroll
  for (int j = 0; j < 4; j++) {
    int b = b0 + j * 16;
    const f32x4 s4 = *reinterpret_cast<const f32x4*>(&st[(b * 4096 + n) * 64 + o0]);
    f16x4 r4 = *reinterpret_cast<const f16x4*>(&rb[(n * 64 + b) * 64 + o0]);
    f32x4 o4;
#pragma unroll
    for (int k = 0; k < 4; k++) {
      float e2 = __expf(2.f * acc[j][k]);
      float hc = 1.f - 2.f / (e2 + 1.f);     // tanh
      float rr = (float)r4[k];
      o4[k] = rr * s4[k] + (1.f - rr) * hc;
    }
    *reinterpret_cast<f32x4*>(&out[(b * 4096 + n) * 64 + o0]) = o4;
  }
}

extern "C" void kernel_launch(void* const* d_in, const int* in_sizes, int n_in,
                              void* d_out, int out_size, void* d_ws, size_t ws_size,
                              hipStream_t stream) {
  const float* x   = (const float*)d_in[0];
  const float* st  = (const float*)d_in[1];
  const float* emb = (const float*)d_in[2];
  const float* gwp = (const float*)d_in[3];
  const float* gbp = (const float*)d_in[4];
  const float* uwp = (const float*)d_in[5];
  const float* ubp = (const float*)d_in[6];
  float* out = (float*)d_out;
  char* ws = (char*)d_ws;

  // slot A [0,33.55M): S for gemm1 -> W_all_g chunks -> S2 for gemm2
  _Float16* slotA = (_Float16*)(ws + 0);
  _Float16* xs_t  = (_Float16*)(ws + 33554432);   // 67 MB [b][c][m]
  _Float16* xg    = (_Float16*)(ws + 100663296);  // 67 MB (gemm1 out; gemm2 overwrites)
  _Float16* zb    = (_Float16*)(ws + 167772160);  // 33.5 MB [n][b][64]; -> W_all_u chunks after cand
  _Float16* rb    = (_Float16*)(ws + 201326592);  // 33.5 MB [n][b][64] (alive to upd)
  float* wtg = (float*)(ws + 234881024);          // 1 MB
  float* wtu = (float*)(ws + 235929600);          // 0.5 MB
  if (ws_size < 236453888ull) return;  // fail loudly rather than corrupt

  k_wpoolT<<<1536, 256, 0, stream>>>(gwp, uwp, wtg, wtu);
  k_supports<<<4096, 256, 0, stream>>>(emb, slotA);
  k_concat<<<dim3(64, 64), 256, 0, stream>>>(x, st, xs_t);
  k_gemm<<<dim3(32, 64), 256, 0, stream>>>(slotA, xs_t, xg);
  // gate in 4 chunks of 1024 nodes; W chunk (33.55 MB) reuses slot A (S dead)
  for (int c = 0; c < 4; c++) {
    k_wall<<<dim3(16, 8), 256, 0, stream>>>(emb, c * 1024, wtg, 16384, slotA);
    k_gate<<<1024, 256, 0, stream>>>(xg, emb, slotA, gbp, c * 1024, zb, rb);
  }
  k_cand<<<dim3(64, 64), 256, 0, stream>>>(zb, st, xs_t);
  k_supports<<<4096, 256, 0, stream>>>(emb, slotA);        // recompute S (cheap)
  k_gemm<<<dim3(32, 64), 256, 0, stream>>>(slotA, xs_t, xg);
  // update in 2 chunks of 2048 nodes; W chunk (33.55 MB) reuses zb slot (dead)
  for (int c = 0; c < 2; c++) {
    k_wall<<<dim3(32, 4), 256, 0, stream>>>(emb, c * 2048, wtu, 8192, zb);
    k_upd<<<2048, 256, 0, stream>>>(xg, emb, zb, ubp, c * 2048, rb, st, out);
  }
}

// Round 10
// 1030.917 us; speedup vs baseline: 2.4044x; 1.1817x over previous
//
#include <hip/hip_runtime.h>

typedef float f32x4 __attribute__((ext_vector_type(4)));
typedef _Float16 f16x8 __attribute__((ext_vector_type(8)));
typedef _Float16 f16x4 __attribute__((ext_vector_type(4)));
typedef _Float16 f16x2 __attribute__((ext_vector_type(2)));

typedef __attribute__((address_space(1))) const unsigned char gbyte;
typedef __attribute__((address_space(3))) unsigned char sbyte;
__device__ __forceinline__ void gload_lds16(const void* gp, void* lp) {
  __builtin_amdgcn_global_load_lds((gbyte*)gp, (sbyte*)lp, 16, 0, 0);
}

// packed f16 dot2 with f32 accumulate (v_dot2_f32_f16); fallback = R8 numerics
#if __has_builtin(__builtin_amdgcn_fdot2)
__device__ __forceinline__ float fdot2(f16x2 a, f16x2 b, float c) {
  return __builtin_amdgcn_fdot2(a, b, c, false);
}
#else
__device__ __forceinline__ float fdot2(f16x2 a, f16x2 b, float c) {
  return c + (float)a[0] * (float)b[0] + (float)a[1] * (float)b[1];
}
#endif

// ---------------- 1. weight-pool transpose to [d][o][i], f32 ----------------
__global__ __launch_bounds__(256) void k_wpoolT(const float* __restrict__ gwp,
                                                const float* __restrict__ uwp,
                                                float* __restrict__ wtg,
                                                float* __restrict__ wtu) {
  int idx = blockIdx.x * 256 + threadIdx.x;
  if (idx < 16 * 128 * 128) {
    int d = idx >> 14, rem = idx & 16383, o = rem >> 7, i = rem & 127;
    wtg[idx] = gwp[(d << 14) + (i << 7) + o];          // gwp[d][i][o]
  } else {
    int j = idx - 16 * 128 * 128;
    if (j < 16 * 64 * 128) {
      int d = j >> 13, rem = j & 8191, o = rem >> 7, i = rem & 127;
      wtu[j] = uwp[(d << 13) + (i << 6) + o];          // uwp[d][i][o(64)]
    }
  }
}

// ---------------- 2. supports = softmax(relu(E E^T)) row-wise, f16 ----------
__global__ __launch_bounds__(256) void k_supports(const float* __restrict__ emb,
                                                  _Float16* __restrict__ S) {
  int n = blockIdx.x, tid = threadIdx.x;
  float en[16];
#pragma unroll
  for (int d = 0; d < 16; d++) en[d] = emb[n * 16 + d];
  float v[16];
  float sum = 0.f;
#pragma unroll
  for (int i = 0; i < 16; i++) {
    int m = i * 256 + tid;
    const float* em = emb + m * 16;
    float acc = 0.f;
#pragma unroll
    for (int d = 0; d < 16; d++) acc += en[d] * em[d];
    acc = fmaxf(acc, 0.f);
    float e = __expf(acc);
    v[i] = e;
    sum += e;
  }
#pragma unroll
  for (int off = 32; off > 0; off >>= 1) sum += __shfl_down(sum, off);
  __shared__ float red[4];
  if ((tid & 63) == 0) red[tid >> 6] = sum;
  __syncthreads();
  float inv = 1.f / (red[0] + red[1] + red[2] + red[3]);
#pragma unroll
  for (int i = 0; i < 16; i++) S[n * 4096 + i * 256 + tid] = (_Float16)(v[i] * inv);
}

// ------- 3. xs_t[b][c][m] = f16(concat(x,state))  (c-major for GEMM B) ------
__global__ __launch_bounds__(256) void k_concat(const float* __restrict__ x,
                                                const float* __restrict__ st,
                                                _Float16* __restrict__ xs_t) {
  int m0 = blockIdx.x * 64, b = blockIdx.y, tid = threadIdx.x;
  __shared__ __attribute__((aligned(16))) _Float16 T[64][130];
#pragma unroll
  for (int i = 0; i < 16; i++) {
    int li = i * 256 + tid;
    int ml = li >> 6, c = li & 63;
    int base = (b * 4096 + m0 + ml) * 64 + c;
    T[ml][c] = (_Float16)x[base];
    T[ml][64 + c] = (_Float16)st[base];
  }
  __syncthreads();
  int cg = tid >> 3, mch = tid & 7;
#pragma unroll
  for (int cb = 0; cb < 4; cb++) {
    int c = cb * 32 + cg;
    f16x8 tmp;
#pragma unroll
    for (int j = 0; j < 8; j++) tmp[j] = T[mch * 8 + j][c];
    *reinterpret_cast<f16x8*>(&xs_t[(b * 128 + c) * 4096 + m0 + mch * 8]) = tmp;
  }
}

// -------- 4. GEMM1: Y[b][n][c] = sum_m S[n][m] * xs_t[b][c][m]  (f16 MFMA) --
// T2 XOR-swizzle, rule-21 form (proven R8): LDS dest linear, global SOURCE
// column pre-swizzled, reads apply the same involution.
__global__ __launch_bounds__(256) void k_gemm(const _Float16* __restrict__ S,
                                              const _Float16* __restrict__ Xt,
                                              _Float16* __restrict__ Y) {
  int nt = blockIdx.x, b = blockIdx.y;
  int tid = threadIdx.x, lane = tid & 63, w = tid >> 6;
  int wr = w >> 1, wc = w & 1;
  __shared__ __attribute__((aligned(16))) _Float16 As[128 * 64];
  __shared__ __attribute__((aligned(16))) _Float16 Bs[128 * 64];
  const _Float16* Sb = S + nt * 128 * 4096;
  const _Float16* Xb = Xt + b * 128 * 4096;
  f32x4 acc[4][4];
#pragma unroll
  for (int m = 0; m < 4; m++)
#pragma unroll
    for (int n = 0; n < 4; n++) acc[m][n] = (f32x4){0.f, 0.f, 0.f, 0.f};

  int lrow = lane >> 3;                       // 0..7 (== row&7 of lane's row)
  int lcolsw = (((lane & 7) ^ lrow) * 8);     // pre-swizzled source column
  int lo = lane & 15, hi = lane >> 4;
  int xs = (lane & 7) * 8;                    // read-side XOR (elem units)
  for (int k0 = 0; k0 < 4096; k0 += 64) {
    __syncthreads();
#pragma unroll
    for (int i = 0; i < 4; i++) {
      int j = w * 4 + i;
      int row = j * 8 + lrow;
      gload_lds16(Sb + row * 4096 + k0 + lcolsw, &As[j * 512]);
      gload_lds16(Xb + row * 4096 + k0 + lcolsw, &Bs[j * 512]);
    }
    __syncthreads();
#pragma unroll
    for (int kk = 0; kk < 2; kk++) {
      int col = (kk * 32 + hi * 8) ^ xs;
      f16x8 af[4], bfr[4];
#pragma unroll
      for (int m = 0; m < 4; m++)
        af[m] = *reinterpret_cast<const f16x8*>(&As[(wr * 64 + m * 16 + lo) * 64 + col]);
#pragma unroll
      for (int n = 0; n < 4; n++)
        bfr[n] = *reinterpret_cast<const f16x8*>(&Bs[(wc * 64 + n * 16 + lo) * 64 + col]);
#pragma unroll
      for (int m = 0; m < 4; m++)
#pragma unroll
        for (int n = 0; n < 4; n++)
          acc[m][n] = __builtin_amdgcn_mfma_f32_16x16x32_f16(af[m], bfr[n], acc[m][n], 0, 0, 0);
    }
  }
  int r0 = (lane >> 4) * 4, cl = lane & 15;
#pragma unroll
  for (int m = 0; m < 4; m++)
#pragma unroll
    for (int r = 0; r < 4; r++) {
      int row = nt * 128 + wr * 64 + m * 16 + r0 + r;
#pragma unroll
      for (int n = 0; n < 4; n++) {
        int c = wc * 64 + n * 16 + cl;
        Y[(b * 4096 + row) * 128 + c] = (_Float16)acc[m][n][r];
      }
    }
}

// -------- 4b. GEMM2 (half-N): only c in [64,128) -- the z*state half.
// S@x half is already in Y from GEMM1 (bit-identical). N-tile spans the
// c>=64 columns of a BATCH PAIR (2*bp, 2*bp+1): tile row r -> global xs_t
// row 256*bp + 64 + (r>>6)*128 + (r&63). MFMA core identical to k_gemm.
__global__ __launch_bounds__(256) void k_gemm2(const _Float16* __restrict__ S,
                                               const _Float16* __restrict__ Xt,
                                               _Float16* __restrict__ Y) {
  int nt = blockIdx.x, bp = blockIdx.y;
  int tid = threadIdx.x, lane = tid & 63, w = tid >> 6;
  int wr = w >> 1, wc = w & 1;
  __shared__ __attribute__((aligned(16))) _Float16 As[128 * 64];
  __shared__ __attribute__((aligned(16))) _Float16 Bs[128 * 64];
  const _Float16* Sb = S + nt * 128 * 4096;
  const _Float16* Xb = Xt + (size_t)(256 * bp + 64) * 4096;
  f32x4 acc[4][4];
#pragma unroll
  for (int m = 0; m < 4; m++)
#pragma unroll
    for (int n = 0; n < 4; n++) acc[m][n] = (f32x4){0.f, 0.f, 0.f, 0.f};

  int lrow = lane >> 3;
  int lcolsw = (((lane & 7) ^ lrow) * 8);
  int lo = lane & 15, hi = lane >> 4;
  int xs = (lane & 7) * 8;
  for (int k0 = 0; k0 < 4096; k0 += 64) {
    __syncthreads();
#pragma unroll
    for (int i = 0; i < 4; i++) {
      int j = w * 4 + i;
      int row = j * 8 + lrow;                              // 0..127 tile row
      int groff = ((row >> 6) * 128 + (row & 63)) * 4096;  // batch-pair map
      gload_lds16(Sb + row * 4096 + k0 + lcolsw, &As[j * 512]);
      gload_lds16(Xb + groff + k0 + lcolsw, &Bs[j * 512]);
    }
    __syncthreads();
#pragma unroll
    for (int kk = 0; kk < 2; kk++) {
      int col = (kk * 32 + hi * 8) ^ xs;
      f16x8 af[4], bfr[4];
#pragma unroll
      for (int m = 0; m < 4; m++)
        af[m] = *reinterpret_cast<const f16x8*>(&As[(wr * 64 + m * 16 + lo) * 64 + col]);
#pragma unroll
      for (int n = 0; n < 4; n++)
        bfr[n] = *reinterpret_cast<const f16x8*>(&Bs[(wc * 64 + n * 16 + lo) * 64 + col]);
#pragma unroll
      for (int m = 0; m < 4; m++)
#pragma unroll
        for (int n = 0; n < 4; n++)
          acc[m][n] = __builtin_amdgcn_mfma_f32_16x16x32_f16(af[m], bfr[n], acc[m][n], 0, 0, 0);
    }
  }
  int r0 = (lane >> 4) * 4, cl = lane & 15;
#pragma unroll
  for (int m = 0; m < 4; m++)
#pragma unroll
    for (int r = 0; r < 4; r++) {
      int row = nt * 128 + wr * 64 + m * 16 + r0 + r;
#pragma unroll
      for (int n = 0; n < 4; n++) {
        int ct = wc * 64 + n * 16 + cl;        // 0..127 tile col
        int batch = 2 * bp + (ct >> 6);
        int c = 64 + (ct & 63);
        Y[((size_t)batch * 4096 + row) * 128 + c] = (_Float16)acc[m][n][r];
      }
    }
}

// ---- 5a. k_wall: W_all[nn][o*i] = f16( sum_d E[n0+nn][d] * wt[d][o*i] ) ----
__global__ __launch_bounds__(256) void k_wall(const float* __restrict__ emb, int n0,
                                              const float* __restrict__ wt, int OI,
                                              _Float16* __restrict__ Wout) {
  int bx = blockIdx.x, by = blockIdx.y, tid = threadIdx.x;
  __shared__ float e_sh[64][16];
  {
    int node = tid >> 2, part = tid & 3;
    f32x4 v = *reinterpret_cast<const f32x4*>(emb + (n0 + bx * 64 + node) * 16 + part * 4);
    *reinterpret_cast<f32x4*>(&e_sh[node][part * 4]) = v;
  }
  __syncthreads();
  int oi0 = by * 2048 + tid * 8;
#pragma unroll
  for (int g = 0; g < 8; g++) {
    f32x4 a0[8], a1[8];
#pragma unroll
    for (int nn = 0; nn < 8; nn++) { a0[nn] = (f32x4){0,0,0,0}; a1[nn] = (f32x4){0,0,0,0}; }
#pragma unroll
    for (int d = 0; d < 16; d++) {
      const f32x4* p = reinterpret_cast<const f32x4*>(wt + d * OI + oi0);
      f32x4 v0 = p[0], v1 = p[1];
#pragma unroll
      for (int nn = 0; nn < 8; nn++) {
        float e = e_sh[g * 8 + nn][d];
        a0[nn] += e * v0;
        a1[nn] += e * v1;
      }
    }
#pragma unroll
    for (int nn = 0; nn < 8; nn++) {
      f16x8 pk;
#pragma unroll
      for (int q = 0; q < 4; q++) { pk[q] = (_Float16)a0[nn][q]; pk[4 + q] = (_Float16)a1[nn][q]; }
      *reinterpret_cast<f16x8*>(Wout + (size_t)(bx * 64 + g * 8 + nn) * OI + oi0) = pk;
    }
  }
}

// ---- 5b. gate (dot2 VALU, precomputed W chunk): sigmoid(x_g @ W_n + b_n) ---
__global__ __launch_bounds__(256) void k_gate(const _Float16* __restrict__ xg,   // [b][n][128]
                                              const float* __restrict__ emb,
                                              const _Float16* __restrict__ Wc,   // chunk [1024][128][128]
                                              const float* __restrict__ gbp,
                                              int n0,
                                              _Float16* __restrict__ zb,         // [n][b][64]
                                              _Float16* __restrict__ rb) {       // [n][b][64]
  int n = n0 + blockIdx.x, tid = threadIdx.x;
  __shared__ __attribute__((aligned(16))) _Float16 A[64][136];
  __shared__ __attribute__((aligned(16))) _Float16 W[128][140];
  __shared__ float bias_sh[128];
  // stage A
  {
    int b = tid >> 2, i0 = (tid & 3) * 32;
    const f16x8* s8 = reinterpret_cast<const f16x8*>(xg + (b * 4096 + n) * 128 + i0);
#pragma unroll
    for (int c = 0; c < 4; c++)
      *reinterpret_cast<f16x8*>(&A[b][i0 + c * 8]) = s8[c];
  }
  // stage W from global chunk (coalesced: 128 contiguous B per thread)
  {
    const _Float16* wrow = Wc + (size_t)blockIdx.x * 16384;
    int o = tid >> 1, ih = tid & 1;
#pragma unroll
    for (int k = 0; k < 8; k++) {
      f16x8 v = *reinterpret_cast<const f16x8*>(wrow + o * 128 + ih * 64 + k * 8);
      f16x4 lo = {v[0], v[1], v[2], v[3]}, hi = {v[4], v[5], v[6], v[7]};
      *reinterpret_cast<f16x4*>(&W[o][ih * 64 + k * 8]) = lo;
      *reinterpret_cast<f16x4*>(&W[o][ih * 64 + k * 8 + 4]) = hi;
    }
  }
  if (tid < 128) {
    float s = 0.f;
#pragma unroll
    for (int d = 0; d < 16; d++) s += emb[n * 16 + d] * gbp[d * 128 + tid];
    bias_sh[tid] = s;
  }
  __syncthreads();
  int b0 = tid & 15, o0 = (tid >> 4) * 8;
  float acc[4][8];
#pragma unroll
  for (int j = 0; j < 4; j++)
#pragma unroll
    for (int k = 0; k < 8; k++) acc[j][k] = bias_sh[o0 + k];
#pragma unroll
  for (int is = 0; is < 128; is += 8) {
    f16x8 av[4];
#pragma unroll
    for (int j = 0; j < 4; j++) av[j] = *reinterpret_cast<const f16x8*>(&A[b0 + j * 16][is]);
    f16x2 ap[4][4];
#pragma unroll
    for (int j = 0; j < 4; j++) {
      ap[j][0] = (f16x2){av[j][0], av[j][1]};
      ap[j][1] = (f16x2){av[j][2], av[j][3]};
      ap[j][2] = (f16x2){av[j][4], av[j][5]};
      ap[j][3] = (f16x2){av[j][6], av[j][7]};
    }
#pragma unroll
    for (int k = 0; k < 8; k++) {
      f16x4 wlo = *reinterpret_cast<const f16x4*>(&W[o0 + k][is]);
      f16x4 whi = *reinterpret_cast<const f16x4*>(&W[o0 + k][is + 4]);
      f16x2 w0 = (f16x2){wlo[0], wlo[1]}, w1 = (f16x2){wlo[2], wlo[3]};
      f16x2 w2 = (f16x2){whi[0], whi[1]}, w3 = (f16x2){whi[2], whi[3]};
#pragma unroll
      for (int j = 0; j < 4; j++) {
        float a = acc[j][k];
        a = fdot2(ap[j][0], w0, a);
        a = fdot2(ap[j][1], w1, a);
        a = fdot2(ap[j][2], w2, a);
        a = fdot2(ap[j][3], w3, a);
        acc[j][k] = a;
      }
    }
  }
#pragma unroll
  for (int j = 0; j < 4; j++) {
    int b = b0 + j * 16;
    f16x8 pk;
#pragma unroll
    for (int k = 0; k < 8; k++) pk[k] = (_Float16)(1.f / (1.f + __expf(-acc[j][k])));
    if (o0 < 64) *reinterpret_cast<f16x8*>(&zb[(n * 64 + b) * 64 + o0]) = pk;
    else         *reinterpret_cast<f16x8*>(&rb[(n * 64 + b) * 64 + (o0 - 64)]) = pk;
  }
}

// ------------- 6. xs_t[b][64+o][m] = f16(z[m][b][o] * state[b][m][o]) -------
__global__ __launch_bounds__(256) void k_cand(const _Float16* __restrict__ zb,
                                              const float* __restrict__ st,
                                              _Float16* __restrict__ xs_t) {
  int m0 = blockIdx.x * 64, b = blockIdx.y, tid = threadIdx.x;
  __shared__ __attribute__((aligned(16))) _Float16 T[64][66];
#pragma unroll
  for (int i = 0; i < 16; i++) {
    int li = i * 256 + tid, ml = li >> 6, o = li & 63;
    float z = (float)zb[((m0 + ml) * 64 + b) * 64 + o];
    float s = st[(b * 4096 + m0 + ml) * 64 + o];
    T[ml][o] = (_Float16)(z * s);
  }
  __syncthreads();
  int og = tid >> 3, mch = tid & 7;
#pragma unroll
  for (int cb = 0; cb < 2; cb++) {
    int o = cb * 32 + og;
    f16x8 tmp;
#pragma unroll
    for (int j = 0; j < 8; j++) tmp[j] = T[mch * 8 + j][o];
    *reinterpret_cast<f16x8*>(&xs_t[(b * 128 + 64 + o) * 4096 + m0 + mch * 8]) = tmp;
  }
}

// ---- 7. update (dot2 VALU, precomputed W chunk): hc=tanh(xg2 @ Wu_n + bu);
//      h = r*state + (1-r)*hc -> out. -----------------------------------------
__global__ __launch_bounds__(256) void k_upd(const _Float16* __restrict__ xg2,   // [b][n][128]
                                             const float* __restrict__ emb,
                                             const _Float16* __restrict__ Wc,    // chunk [2048][64][128]
                                             const float* __restrict__ ubp,
                                             int n0,
                                             const _Float16* __restrict__ rb,    // [n][b][64]
                                             const float* __restrict__ st,
                                             float* __restrict__ out) {
  int n = n0 + blockIdx.x, tid = threadIdx.x;
  __shared__ __attribute__((aligned(16))) _Float16 A[64][136];
  __shared__ __attribute__((aligned(16))) _Float16 W[64][140];
  __shared__ float bias_sh[64];
  // stage A
  {
    int b = tid >> 2, i0 = (tid & 3) * 32;
    const f16x8* s8 = reinterpret_cast<const f16x8*>(xg2 + (b * 4096 + n) * 128 + i0);
#pragma unroll
    for (int c = 0; c < 4; c++)
      *reinterpret_cast<f16x8*>(&A[b][i0 + c * 8]) = s8[c];
  }
  // stage W (quarter-row per thread, 64 contiguous B)
  {
    const _Float16* wrow = Wc + (size_t)blockIdx.x * 8192;
    int o = tid >> 2, q4 = tid & 3;
#pragma unroll
    for (int k = 0; k < 4; k++) {
      f16x8 v = *reinterpret_cast<const f16x8*>(wrow + o * 128 + q4 * 32 + k * 8);
      f16x4 lo = {v[0], v[1], v[2], v[3]}, hi = {v[4], v[5], v[6], v[7]};
      *reinterpret_cast<f16x4*>(&W[o][q4 * 32 + k * 8]) = lo;
      *reinterpret_cast<f16x4*>(&W[o][q4 * 32 + k * 8 + 4]) = hi;
    }
  }
  if (tid < 64) {
    float s = 0.f;
#pragma unroll
    for (int d = 0; d < 16; d++) s += emb[n * 16 + d] * ubp[d * 64 + tid];
    bias_sh[tid] = s;
  }
  __syncthreads();
  int b0 = tid & 15, o0 = (tid >> 4) * 4;
  float acc[4][4];
#pragma unroll
  for (int j = 0; j < 4; j++)
#pragma unroll
    for (int k = 0; k < 4; k++) acc[j][k] = bias_sh[o0 + k];
#pragma unroll
  for (int is = 0; is < 128; is += 8) {
    f16x8 av[4];
#pragma unroll
    for (int j = 0; j < 4; j++) av[j] = *reinterpret_cast<const f16x8*>(&A[b0 + j * 16][is]);
    f16x2 ap[4][4];
#pragma unroll
    for (int j = 0; j < 4; j++) {
      ap[j][0] = (f16x2){av[j][0], av[j][1]};
      ap[j][1] = (f16x2){av[j][2], av[j][3]};
      ap[j][2] = (f16x2){av[j][4], av[j][5]};
      ap[j][3] = (f16x2){av[j][6], av[j][7]};
    }
#pragma unroll
    for (int k = 0; k < 4; k++) {
      f16x4 wlo = *reinterpret_cast<const f16x4*>(&W[o0 + k][is]);
      f16x4 whi = *reinterpret_cast<const f16x4*>(&W[o0 + k][is + 4]);
      f16x2 w0 = (f16x2){wlo[0], wlo[1]}, w1 = (f16x2){wlo[2], wlo[3]};
      f16x2 w2 = (f16x2){whi[0], whi[1]}, w3 = (f16x2){whi[2], whi[3]};
#pragma unroll
      for (int j = 0; j < 4; j++) {
        float a = acc[j][k];
        a = fdot2(ap[j][0], w0, a);
        a = fdot2(ap[j][1], w1, a);
        a = fdot2(ap[j][2], w2, a);
        a = fdot2(ap[j][3], w3, a);
        acc[j][k] = a;
      }
    }
  }
#pragma unroll
  for (int j = 0; j < 4; j++) {
    int b = b0 + j * 16;
    const f32x4 s4 = *reinterpret_cast<const f32x4*>(&st[(b * 4096 + n) * 64 + o0]);
    f16x4 r4 = *reinterpret_cast<const f16x4*>(&rb[(n * 64 + b) * 64 + o0]);
    f32x4 o4;
#pragma unroll
    for (int k = 0; k < 4; k++) {
      float e2 = __expf(2.f * acc[j][k]);
      float hc = 1.f - 2.f / (e2 + 1.f);     // tanh
      float rr = (float)r4[k];
      o4[k] = rr * s4[k] + (1.f - rr) * hc;
    }
    *reinterpret_cast<f32x4*>(&out[(b * 4096 + n) * 64 + o0]) = o4;
  }
}

extern "C" void kernel_launch(void* const* d_in, const int* in_sizes, int n_in,
                              void* d_out, int out_size, void* d_ws, size_t ws_size,
                              hipStream_t stream) {
  const float* x   = (const float*)d_in[0];
  const float* st  = (const float*)d_in[1];
  const float* emb = (const float*)d_in[2];
  const float* gwp = (const float*)d_in[3];
  const float* gbp = (const float*)d_in[4];
  const float* uwp = (const float*)d_in[5];
  const float* ubp = (const float*)d_in[6];
  float* out = (float*)d_out;
  char* ws = (char*)d_ws;

  // slot A [0,33.55M): S for gemm1 -> W_all_g chunks -> S2 for gemm2
  _Float16* slotA = (_Float16*)(ws + 0);
  _Float16* xs_t  = (_Float16*)(ws + 33554432);   // 67 MB [b][c][m]
  _Float16* xg    = (_Float16*)(ws + 100663296);  // 67 MB (gemm1 out; gemm2 fills c>=64)
  _Float16* zb    = (_Float16*)(ws + 167772160);  // 33.5 MB [n][b][64]; -> W_all_u chunks after cand
  _Float16* rb    = (_Float16*)(ws + 201326592);  // 33.5 MB [n][b][64] (alive to upd)
  float* wtg = (float*)(ws + 234881024);          // 1 MB
  float* wtu = (float*)(ws + 235929600);          // 0.5 MB
  if (ws_size < 236453888ull) return;  // fail loudly rather than corrupt

  k_wpoolT<<<1536, 256, 0, stream>>>(gwp, uwp, wtg, wtu);
  k_supports<<<4096, 256, 0, stream>>>(emb, slotA);
  k_concat<<<dim3(64, 64), 256, 0, stream>>>(x, st, xs_t);
  k_gemm<<<dim3(32, 64), 256, 0, stream>>>(slotA, xs_t, xg);
  // gate in 4 chunks of 1024 nodes; W chunk (33.55 MB) reuses slot A (S dead)
  for (int c = 0; c < 4; c++) {
    k_wall<<<dim3(16, 8), 256, 0, stream>>>(emb, c * 1024, wtg, 16384, slotA);
    k_gate<<<1024, 256, 0, stream>>>(xg, emb, slotA, gbp, c * 1024, zb, rb);
  }
  k_cand<<<dim3(64, 64), 256, 0, stream>>>(zb, st, xs_t);
  k_supports<<<4096, 256, 0, stream>>>(emb, slotA);        // recompute S (cheap)
  // GEMM2: only the z*state half (c>=64); S@x half kept from GEMM1 in xg
  k_gemm2<<<dim3(32, 32), 256, 0, stream>>>(slotA, xs_t, xg);
  // update in 2 chunks of 2048 nodes; W chunk (33.55 MB) reuses zb slot (dead)
  for (int c = 0; c < 2; c++) {
    k_wall<<<dim3(32, 4), 256, 0, stream>>>(emb, c * 2048, wtu, 8192, zb);
    k_upd<<<2048, 256, 0, stream>>>(xg, emb, zb, ubp, c * 2048, rb, st, out);
  }
}

// Round 11
// 1019.964 us; speedup vs baseline: 2.4302x; 1.0107x over previous
//
#include <hip/hip_runtime.h>

typedef float f32x4 __attribute__((ext_vector_type(4)));
typedef float f32x16 __attribute__((ext_vector_type(16)));
typedef _Float16 f16x8 __attribute__((ext_vector_type(8)));
typedef _Float16 f16x4 __attribute__((ext_vector_type(4)));
typedef _Float16 f16x2 __attribute__((ext_vector_type(2)));

typedef __attribute__((address_space(1))) const unsigned char gbyte;
typedef __attribute__((address_space(3))) unsigned char sbyte;
__device__ __forceinline__ void gload_lds16(const void* gp, void* lp) {
  __builtin_amdgcn_global_load_lds((gbyte*)gp, (sbyte*)lp, 16, 0, 0);
}

// packed f16 dot2 with f32 accumulate (v_dot2_f32_f16); fallback = R8 numerics
#if __has_builtin(__builtin_amdgcn_fdot2)
__device__ __forceinline__ float fdot2(f16x2 a, f16x2 b, float c) {
  return __builtin_amdgcn_fdot2(a, b, c, false);
}
#else
__device__ __forceinline__ float fdot2(f16x2 a, f16x2 b, float c) {
  return c + (float)a[0] * (float)b[0] + (float)a[1] * (float)b[1];
}
#endif

// ---------------- 1. weight-pool transpose to [d][o][i], f32 ----------------
__global__ __launch_bounds__(256) void k_wpoolT(const float* __restrict__ gwp,
                                                const float* __restrict__ uwp,
                                                float* __restrict__ wtg,
                                                float* __restrict__ wtu) {
  int idx = blockIdx.x * 256 + threadIdx.x;
  if (idx < 16 * 128 * 128) {
    int d = idx >> 14, rem = idx & 16383, o = rem >> 7, i = rem & 127;
    wtg[idx] = gwp[(d << 14) + (i << 7) + o];          // gwp[d][i][o]
  } else {
    int j = idx - 16 * 128 * 128;
    if (j < 16 * 64 * 128) {
      int d = j >> 13, rem = j & 8191, o = rem >> 7, i = rem & 127;
      wtu[j] = uwp[(d << 13) + (i << 6) + o];          // uwp[d][i][o(64)]
    }
  }
}

// ---------------- 2. supports = softmax(relu(E E^T)) row-wise, f16 ----------
__global__ __launch_bounds__(256) void k_supports(const float* __restrict__ emb,
                                                  _Float16* __restrict__ S) {
  int n = blockIdx.x, tid = threadIdx.x;
  float en[16];
#pragma unroll
  for (int d = 0; d < 16; d++) en[d] = emb[n * 16 + d];
  float v[16];
  float sum = 0.f;
#pragma unroll
  for (int i = 0; i < 16; i++) {
    int m = i * 256 + tid;
    const float* em = emb + m * 16;
    float acc = 0.f;
#pragma unroll
    for (int d = 0; d < 16; d++) acc += en[d] * em[d];
    acc = fmaxf(acc, 0.f);
    float e = __expf(acc);
    v[i] = e;
    sum += e;
  }
#pragma unroll
  for (int off = 32; off > 0; off >>= 1) sum += __shfl_down(sum, off);
  __shared__ float red[4];
  if ((tid & 63) == 0) red[tid >> 6] = sum;
  __syncthreads();
  float inv = 1.f / (red[0] + red[1] + red[2] + red[3]);
#pragma unroll
  for (int i = 0; i < 16; i++) S[n * 4096 + i * 256 + tid] = (_Float16)(v[i] * inv);
}

// ------- 3. xs_t[b][c][m] = f16(concat(x,state))  (c-major for GEMM B) ------
__global__ __launch_bounds__(256) void k_concat(const float* __restrict__ x,
                                                const float* __restrict__ st,
                                                _Float16* __restrict__ xs_t) {
  int m0 = blockIdx.x * 64, b = blockIdx.y, tid = threadIdx.x;
  __shared__ __attribute__((aligned(16))) _Float16 T[64][130];
#pragma unroll
  for (int i = 0; i < 16; i++) {
    int li = i * 256 + tid;
    int ml = li >> 6, c = li & 63;
    int base = (b * 4096 + m0 + ml) * 64 + c;
    T[ml][c] = (_Float16)x[base];
    T[ml][64 + c] = (_Float16)st[base];
  }
  __syncthreads();
  int cg = tid >> 3, mch = tid & 7;
#pragma unroll
  for (int cb = 0; cb < 4; cb++) {
    int c = cb * 32 + cg;
    f16x8 tmp;
#pragma unroll
    for (int j = 0; j < 8; j++) tmp[j] = T[mch * 8 + j][c];
    *reinterpret_cast<f16x8*>(&xs_t[(b * 128 + c) * 4096 + m0 + mch * 8]) = tmp;
  }
}

// -------- 4. GEMM1: Y[b][n][c] = sum_m S[n][m] * xs_t[b][c][m] --------------
// 32x32x16 MFMA (2x FLOP per fragment-read vs 16x16x32 -> halves LDS reads).
// Staging + T2 XOR swizzle identical to the R8/R10-proven path; read-side
// applies the same involution on the new 8-elem granules.
// A/B frag: row/col = lane&31, k = (lane>>5)*8 + j.
// C/D (HW-verified m74/m101): col = lane&31, row = (reg&3)+8*(reg>>2)+4*(lane>>5).
__global__ __launch_bounds__(256) void k_gemm(const _Float16* __restrict__ S,
                                              const _Float16* __restrict__ Xt,
                                              _Float16* __restrict__ Y) {
  int nt = blockIdx.x, b = blockIdx.y;
  int tid = threadIdx.x, lane = tid & 63, w = tid >> 6;
  int wr = w >> 1, wc = w & 1;
  __shared__ __attribute__((aligned(16))) _Float16 As[128 * 64];
  __shared__ __attribute__((aligned(16))) _Float16 Bs[128 * 64];
  const _Float16* Sb = S + nt * 128 * 4096;
  const _Float16* Xb = Xt + b * 128 * 4096;
  f32x16 acc[2][2];
#pragma unroll
  for (int fm = 0; fm < 2; fm++)
#pragma unroll
    for (int fn = 0; fn < 2; fn++)
#pragma unroll
      for (int q = 0; q < 16; q++) acc[fm][fn][q] = 0.f;

  int lrow = lane >> 3;                       // staging row-within-group
  int lcolsw = (((lane & 7) ^ lrow) * 8);     // pre-swizzled source column
  int r32 = lane & 31, hi32 = lane >> 5;
  int swz = (r32 & 7) * 8;                    // read-side XOR (elem units)
  for (int k0 = 0; k0 < 4096; k0 += 64) {
    __syncthreads();
#pragma unroll
    for (int i = 0; i < 4; i++) {
      int j = w * 4 + i;
      int row = j * 8 + lrow;
      gload_lds16(Sb + row * 4096 + k0 + lcolsw, &As[j * 512]);
      gload_lds16(Xb + row * 4096 + k0 + lcolsw, &Bs[j * 512]);
    }
    __syncthreads();
#pragma unroll
    for (int kk = 0; kk < 4; kk++) {
      int col = (kk * 16 + hi32 * 8) ^ swz;
      f16x8 af[2], bf[2];
#pragma unroll
      for (int fm = 0; fm < 2; fm++)
        af[fm] = *reinterpret_cast<const f16x8*>(&As[(wr * 64 + fm * 32 + r32) * 64 + col]);
#pragma unroll
      for (int fn = 0; fn < 2; fn++)
        bf[fn] = *reinterpret_cast<const f16x8*>(&Bs[(wc * 64 + fn * 32 + r32) * 64 + col]);
#pragma unroll
      for (int fm = 0; fm < 2; fm++)
#pragma unroll
        for (int fn = 0; fn < 2; fn++)
          acc[fm][fn] = __builtin_amdgcn_mfma_f32_32x32x16_f16(af[fm], bf[fn], acc[fm][fn], 0, 0, 0);
    }
  }
#pragma unroll
  for (int fm = 0; fm < 2; fm++)
#pragma unroll
    for (int fn = 0; fn < 2; fn++)
#pragma unroll
      for (int reg = 0; reg < 16; reg++) {
        int row = nt * 128 + wr * 64 + fm * 32 + (reg & 3) + 8 * (reg >> 2) + 4 * hi32;
        int c = wc * 64 + fn * 32 + r32;
        Y[(b * 4096 + row) * 128 + c] = (_Float16)acc[fm][fn][reg];
      }
}

// -------- 4b. GEMM2 (half-N, 32x32x16): only c in [64,128) -- z*state half.
// N-tile spans the c>=64 columns of batch pair (2bp, 2bp+1); staging row r ->
// global xs_t row 256*bp + 64 + (r>>6)*128 + (r&63). Core identical to k_gemm.
__global__ __launch_bounds__(256) void k_gemm2(const _Float16* __restrict__ S,
                                               const _Float16* __restrict__ Xt,
                                               _Float16* __restrict__ Y) {
  int nt = blockIdx.x, bp = blockIdx.y;
  int tid = threadIdx.x, lane = tid & 63, w = tid >> 6;
  int wr = w >> 1, wc = w & 1;
  __shared__ __attribute__((aligned(16))) _Float16 As[128 * 64];
  __shared__ __attribute__((aligned(16))) _Float16 Bs[128 * 64];
  const _Float16* Sb = S + nt * 128 * 4096;
  const _Float16* Xb = Xt + (size_t)(256 * bp + 64) * 4096;
  f32x16 acc[2][2];
#pragma unroll
  for (int fm = 0; fm < 2; fm++)
#pragma unroll
    for (int fn = 0; fn < 2; fn++)
#pragma unroll
      for (int q = 0; q < 16; q++) acc[fm][fn][q] = 0.f;

  int lrow = lane >> 3;
  int lcolsw = (((lane & 7) ^ lrow) * 8);
  int r32 = lane & 31, hi32 = lane >> 5;
  int swz = (r32 & 7) * 8;
  for (int k0 = 0; k0 < 4096; k0 += 64) {
    __syncthreads();
#pragma unroll
    for (int i = 0; i < 4; i++) {
      int j = w * 4 + i;
      int row = j * 8 + lrow;                              // 0..127 tile row
      int groff = ((row >> 6) * 128 + (row & 63)) * 4096;  // batch-pair map
      gload_lds16(Sb + row * 4096 + k0 + lcolsw, &As[j * 512]);
      gload_lds16(Xb + groff + k0 + lcolsw, &Bs[j * 512]);
    }
    __syncthreads();
#pragma unroll
    for (int kk = 0; kk < 4; kk++) {
      int col = (kk * 16 + hi32 * 8) ^ swz;
      f16x8 af[2], bf[2];
#pragma unroll
      for (int fm = 0; fm < 2; fm++)
        af[fm] = *reinterpret_cast<const f16x8*>(&As[(wr * 64 + fm * 32 + r32) * 64 + col]);
#pragma unroll
      for (int fn = 0; fn < 2; fn++)
        bf[fn] = *reinterpret_cast<const f16x8*>(&Bs[(wc * 64 + fn * 32 + r32) * 64 + col]);
#pragma unroll
      for (int fm = 0; fm < 2; fm++)
#pragma unroll
        for (int fn = 0; fn < 2; fn++)
          acc[fm][fn] = __builtin_amdgcn_mfma_f32_32x32x16_f16(af[fm], bf[fn], acc[fm][fn], 0, 0, 0);
    }
  }
#pragma unroll
  for (int fm = 0; fm < 2; fm++)
#pragma unroll
    for (int fn = 0; fn < 2; fn++)
#pragma unroll
      for (int reg = 0; reg < 16; reg++) {
        int row = nt * 128 + wr * 64 + fm * 32 + (reg & 3) + 8 * (reg >> 2) + 4 * hi32;
        int ct = wc * 64 + fn * 32 + r32;       // 0..127 tile col
        int batch = 2 * bp + (ct >> 6);
        int c = 64 + (ct & 63);
        Y[((size_t)batch * 4096 + row) * 128 + c] = (_Float16)acc[fm][fn][reg];
      }
}

// ---- 5a. k_wall: W_all[nn][o*i] = f16( sum_d E[n0+nn][d] * wt[d][o*i] ) ----
__global__ __launch_bounds__(256) void k_wall(const float* __restrict__ emb, int n0,
                                              const float* __restrict__ wt, int OI,
                                              _Float16* __restrict__ Wout) {
  int bx = blockIdx.x, by = blockIdx.y, tid = threadIdx.x;
  __shared__ float e_sh[64][16];
  {
    int node = tid >> 2, part = tid & 3;
    f32x4 v = *reinterpret_cast<const f32x4*>(emb + (n0 + bx * 64 + node) * 16 + part * 4);
    *reinterpret_cast<f32x4*>(&e_sh[node][part * 4]) = v;
  }
  __syncthreads();
  int oi0 = by * 2048 + tid * 8;
#pragma unroll
  for (int g = 0; g < 8; g++) {
    f32x4 a0[8], a1[8];
#pragma unroll
    for (int nn = 0; nn < 8; nn++) { a0[nn] = (f32x4){0,0,0,0}; a1[nn] = (f32x4){0,0,0,0}; }
#pragma unroll
    for (int d = 0; d < 16; d++) {
      const f32x4* p = reinterpret_cast<const f32x4*>(wt + d * OI + oi0);
      f32x4 v0 = p[0], v1 = p[1];
#pragma unroll
      for (int nn = 0; nn < 8; nn++) {
        float e = e_sh[g * 8 + nn][d];
        a0[nn] += e * v0;
        a1[nn] += e * v1;
      }
    }
#pragma unroll
    for (int nn = 0; nn < 8; nn++) {
      f16x8 pk;
#pragma unroll
      for (int q = 0; q < 4; q++) { pk[q] = (_Float16)a0[nn][q]; pk[4 + q] = (_Float16)a1[nn][q]; }
      *reinterpret_cast<f16x8*>(Wout + (size_t)(bx * 64 + g * 8 + nn) * OI + oi0) = pk;
    }
  }
}

// ---- 5b. gate (dot2 VALU, precomputed W chunk): sigmoid(x_g @ W_n + b_n) ---
__global__ __launch_bounds__(256) void k_gate(const _Float16* __restrict__ xg,   // [b][n][128]
                                              const float* __restrict__ emb,
                                              const _Float16* __restrict__ Wc,   // chunk [1024][128][128]
                                              const float* __restrict__ gbp,
                                              int n0,
                                              _Float16* __restrict__ zb,         // [n][b][64]
                                              _Float16* __restrict__ rb) {       // [n][b][64]
  int n = n0 + blockIdx.x, tid = threadIdx.x;
  __shared__ __attribute__((aligned(16))) _Float16 A[64][136];
  __shared__ __attribute__((aligned(16))) _Float16 W[128][140];
  __shared__ float bias_sh[128];
  // stage A
  {
    int b = tid >> 2, i0 = (tid & 3) * 32;
    const f16x8* s8 = reinterpret_cast<const f16x8*>(xg + (b * 4096 + n) * 128 + i0);
#pragma unroll
    for (int c = 0; c < 4; c++)
      *reinterpret_cast<f16x8*>(&A[b][i0 + c * 8]) = s8[c];
  }
  // stage W from global chunk (coalesced: 128 contiguous B per thread)
  {
    const _Float16* wrow = Wc + (size_t)blockIdx.x * 16384;
    int o = tid >> 1, ih = tid & 1;
#pragma unroll
    for (int k = 0; k < 8; k++) {
      f16x8 v = *reinterpret_cast<const f16x8*>(wrow + o * 128 + ih * 64 + k * 8);
      f16x4 lo = {v[0], v[1], v[2], v[3]}, hi = {v[4], v[5], v[6], v[7]};
      *reinterpret_cast<f16x4*>(&W[o][ih * 64 + k * 8]) = lo;
      *reinterpret_cast<f16x4*>(&W[o][ih * 64 + k * 8 + 4]) = hi;
    }
  }
  if (tid < 128) {
    float s = 0.f;
#pragma unroll
    for (int d = 0; d < 16; d++) s += emb[n * 16 + d] * gbp[d * 128 + tid];
    bias_sh[tid] = s;
  }
  __syncthreads();
  int b0 = tid & 15, o0 = (tid >> 4) * 8;
  float acc[4][8];
#pragma unroll
  for (int j = 0; j < 4; j++)
#pragma unroll
    for (int k = 0; k < 8; k++) acc[j][k] = bias_sh[o0 + k];
#pragma unroll
  for (int is = 0; is < 128; is += 8) {
    f16x8 av[4];
#pragma unroll
    for (int j = 0; j < 4; j++) av[j] = *reinterpret_cast<const f16x8*>(&A[b0 + j * 16][is]);
    f16x2 ap[4][4];
#pragma unroll
    for (int j = 0; j < 4; j++) {
      ap[j][0] = (f16x2){av[j][0], av[j][1]};
      ap[j][1] = (f16x2){av[j][2], av[j][3]};
      ap[j][2] = (f16x2){av[j][4], av[j][5]};
      ap[j][3] = (f16x2){av[j][6], av[j][7]};
    }
#pragma unroll
    for (int k = 0; k < 8; k++) {
      f16x4 wlo = *reinterpret_cast<const f16x4*>(&W[o0 + k][is]);
      f16x4 whi = *reinterpret_cast<const f16x4*>(&W[o0 + k][is + 4]);
      f16x2 w0 = (f16x2){wlo[0], wlo[1]}, w1 = (f16x2){wlo[2], wlo[3]};
      f16x2 w2 = (f16x2){whi[0], whi[1]}, w3 = (f16x2){whi[2], whi[3]};
#pragma unroll
      for (int j = 0; j < 4; j++) {
        float a = acc[j][k];
        a = fdot2(ap[j][0], w0, a);
        a = fdot2(ap[j][1], w1, a);
        a = fdot2(ap[j][2], w2, a);
        a = fdot2(ap[j][3], w3, a);
        acc[j][k] = a;
      }
    }
  }
#pragma unroll
  for (int j = 0; j < 4; j++) {
    int b = b0 + j * 16;
    f16x8 pk;
#pragma unroll
    for (int k = 0; k < 8; k++) pk[k] = (_Float16)(1.f / (1.f + __expf(-acc[j][k])));
    if (o0 < 64) *reinterpret_cast<f16x8*>(&zb[(n * 64 + b) * 64 + o0]) = pk;
    else         *reinterpret_cast<f16x8*>(&rb[(n * 64 + b) * 64 + (o0 - 64)]) = pk;
  }
}

// ------------- 6. xs_t[b][64+o][m] = f16(z[m][b][o] * state[b][m][o]) -------
__global__ __launch_bounds__(256) void k_cand(const _Float16* __restrict__ zb,
                                              const float* __restrict__ st,
                                              _Float16* __restrict__ xs_t) {
  int m0 = blockIdx.x * 64, b = blockIdx.y, tid = threadIdx.x;
  __shared__ __attribute__((aligned(16))) _Float16 T[64][66];
#pragma unroll
  for (int i = 0; i < 16; i++) {
    int li = i * 256 + tid, ml = li >> 6, o = li & 63;
    float z = (float)zb[((m0 + ml) * 64 + b) * 64 + o];
    float s = st[(b * 4096 + m0 + ml) * 64 + o];
    T[ml][o] = (_Float16)(z * s);
  }
  __syncthreads();
  int og = tid >> 3, mch = tid & 7;
#pragma unroll
  for (int cb = 0; cb < 2; cb++) {
    int o = cb * 32 + og;
    f16x8 tmp;
#pragma unroll
    for (int j = 0; j < 8; j++) tmp[j] = T[mch * 8 + j][o];
    *reinterpret_cast<f16x8*>(&xs_t[(b * 128 + 64 + o) * 4096 + m0 + mch * 8]) = tmp;
  }
}

// ---- 7. update (dot2 VALU, precomputed W chunk): hc=tanh(xg2 @ Wu_n + bu);
//      h = r*state + (1-r)*hc -> out. -----------------------------------------
__global__ __launch_bounds__(256) void k_upd(const _Float16* __restrict__ xg2,   // [b][n][128]
                                             const float* __restrict__ emb,
                                             const _Float16* __restrict__ Wc,    // chunk [2048][64][128]
                                             const float* __restrict__ ubp,
                                             int n0,
                                             const _Float16* __restrict__ rb,    // [n][b][64]
                                             const float* __restrict__ st,
                                             float* __restrict__ out) {
  int n = n0 + blockIdx.x, tid = threadIdx.x;
  __shared__ __attribute__((aligned(16))) _Float16 A[64][136];
  __shared__ __attribute__((aligned(16))) _Float16 W[64][140];
  __shared__ float bias_sh[64];
  // stage A
  {
    int b = tid >> 2, i0 = (tid & 3) * 32;
    const f16x8* s8 = reinterpret_cast<const f16x8*>(xg2 + (b * 4096 + n) * 128 + i0);
#pragma unroll
    for (int c = 0; c < 4; c++)
      *reinterpret_cast<f16x8*>(&A[b][i0 + c * 8]) = s8[c];
  }
  // stage W (quarter-row per thread, 64 contiguous B)
  {
    const _Float16* wrow = Wc + (size_t)blockIdx.x * 8192;
    int o = tid >> 2, q4 = tid & 3;
#pragma unroll
    for (int k = 0; k < 4; k++) {
      f16x8 v = *reinterpret_cast<const f16x8*>(wrow + o * 128 + q4 * 32 + k * 8);
      f16x4 lo = {v[0], v[1], v[2], v[3]}, hi = {v[4], v[5], v[6], v[7]};
      *reinterpret_cast<f16x4*>(&W[o][q4 * 32 + k * 8]) = lo;
      *reinterpret_cast<f16x4*>(&W[o][q4 * 32 + k * 8 + 4]) = hi;
    }
  }
  if (tid < 64) {
    float s = 0.f;
#pragma unroll
    for (int d = 0; d < 16; d++) s += emb[n * 16 + d] * ubp[d * 64 + tid];
    bias_sh[tid] = s;
  }
  __syncthreads();
  int b0 = tid & 15, o0 = (tid >> 4) * 4;
  float acc[4][4];
#pragma unroll
  for (int j = 0; j < 4; j++)
#pragma unroll
    for (int k = 0; k < 4; k++) acc[j][k] = bias_sh[o0 + k];
#pragma unroll
  for (int is = 0; is < 128; is += 8) {
    f16x8 av[4];
#pragma unroll
    for (int j = 0; j < 4; j++) av[j] = *reinterpret_cast<const f16x8*>(&A[b0 + j * 16][is]);
    f16x2 ap[4][4];
#pragma unroll
    for (int j = 0; j < 4; j++) {
      ap[j][0] = (f16x2){av[j][0], av[j][1]};
      ap[j][1] = (f16x2){av[j][2], av[j][3]};
      ap[j][2] = (f16x2){av[j][4], av[j][5]};
      ap[j][3] = (f16x2){av[j][6], av[j][7]};
    }
#pragma unroll
    for (int k = 0; k < 4; k++) {
      f16x4 wlo = *reinterpret_cast<const f16x4*>(&W[o0 + k][is]);
      f16x4 whi = *reinterpret_cast<const f16x4*>(&W[o0 + k][is + 4]);
      f16x2 w0 = (f16x2){wlo[0], wlo[1]}, w1 = (f16x2){wlo[2], wlo[3]};
      f16x2 w2 = (f16x2){whi[0], whi[1]}, w3 = (f16x2){whi[2], whi[3]};
#pragma unroll
      for (int j = 0; j < 4; j++) {
        float a = acc[j][k];
        a = fdot2(ap[j][0], w0, a);
        a = fdot2(ap[j][1], w1, a);
        a = fdot2(ap[j][2], w2, a);
        a = fdot2(ap[j][3], w3, a);
        acc[j][k] = a;
      }
    }
  }
#pragma unroll
  for (int j = 0; j < 4; j++) {
    int b = b0 + j * 16;
    const f32x4 s4 = *reinterpret_cast<const f32x4*>(&st[(b * 4096 + n) * 64 + o0]);
    f16x4 r4 = *reinterpret_cast<const f16x4*>(&rb[(n * 64 + b) * 64 + o0]);
    f32x4 o4;
#pragma unroll
    for (int k = 0; k < 4; k++) {
      float e2 = __expf(2.f * acc[j][k]);
      float hc = 1.f - 2.f / (e2 + 1.f);     // tanh
      float rr = (float)r4[k];
      o4[k] = rr * s4[k] + (1.f - rr) * hc;
    }
    *reinterpret_cast<f32x4*>(&out[(b * 4096 + n) * 64 + o0]) = o4;
  }
}

extern "C" void kernel_launch(void* const* d_in, const int* in_sizes, int n_in,
                              void* d_out, int out_size, void* d_ws, size_t ws_size,
                              hipStream_t stream) {
  const float* x   = (const float*)d_in[0];
  const float* st  = (const float*)d_in[1];
  const float* emb = (const float*)d_in[2];
  const float* gwp = (const float*)d_in[3];
  const float* gbp = (const float*)d_in[4];
  const float* uwp = (const float*)d_in[5];
  const float* ubp = (const float*)d_in[6];
  float* out = (float*)d_out;
  char* ws = (char*)d_ws;

  // slot A [0,33.55M): S for gemm1 -> W_all_g chunks -> S2 for gemm2
  _Float16* slotA = (_Float16*)(ws + 0);
  _Float16* xs_t  = (_Float16*)(ws + 33554432);   // 67 MB [b][c][m]
  _Float16* xg    = (_Float16*)(ws + 100663296);  // 67 MB (gemm1 out; gemm2 fills c>=64)
  _Float16* zb    = (_Float16*)(ws + 167772160);  // 33.5 MB [n][b][64]; -> W_all_u chunks after cand
  _Float16* rb    = (_Float16*)(ws + 201326592);  // 33.5 MB [n][b][64] (alive to upd)
  float* wtg = (float*)(ws + 234881024);          // 1 MB
  float* wtu = (float*)(ws + 235929600);          // 0.5 MB
  if (ws_size < 236453888ull) return;  // fail loudly rather than corrupt

  k_wpoolT<<<1536, 256, 0, stream>>>(gwp, uwp, wtg, wtu);
  k_supports<<<4096, 256, 0, stream>>>(emb, slotA);
  k_concat<<<dim3(64, 64), 256, 0, stream>>>(x, st, xs_t);
  k_gemm<<<dim3(32, 64), 256, 0, stream>>>(slotA, xs_t, xg);
  // gate in 4 chunks of 1024 nodes; W chunk (33.55 MB) reuses slot A (S dead)
  for (int c = 0; c < 4; c++) {
    k_wall<<<dim3(16, 8), 256, 0, stream>>>(emb, c * 1024, wtg, 16384, slotA);
    k_gate<<<1024, 256, 0, stream>>>(xg, emb, slotA, gbp, c * 1024, zb, rb);
  }
  k_cand<<<dim3(64, 64), 256, 0, stream>>>(zb, st, xs_t);
  k_supports<<<4096, 256, 0, stream>>>(emb, slotA);        // recompute S (cheap)
  // GEMM2: only the z*state half (c>=64); S@x half kept from GEMM1 in xg
  k_gemm2<<<dim3(32, 32), 256, 0, stream>>>(slotA, xs_t, xg);
  // update in 2 chunks of 2048 nodes; W chunk (33.55 MB) reuses zb slot (dead)
  for (int c = 0; c < 2; c++) {
    k_wall<<<dim3(32, 4), 256, 0, stream>>>(emb, c * 2048, wtu, 8192, zb);
    k_upd<<<2048, 256, 0, stream>>>(xg, emb, zb, ubp, c * 2048, rb, st, out);
  }
}